// Round 1
// baseline (554.147 us; speedup 1.0000x reference)
//
#include <hip/hip_runtime.h>
#include <math.h>

#define B_ 2
#define N_ 4096
#define DIM_ 256
#define HEADS_ 4
#define DH_ 64
#define KNN_ 32
#define INNER_ 256       // HEADS*DH
#define QKVW_ 768        // 3*INNER

static __device__ __forceinline__ unsigned long long ullmin2(unsigned long long a, unsigned long long b) {
    return a < b ? a : b;
}

// ---------------- Kernel A: exact KNN (top-32 by (dist, index)) ----------------
__global__ __launch_bounds__(256) void knn_kernel(const float* __restrict__ coors,
                                                  int* __restrict__ nbhd) {
    __shared__ unsigned long long keys[N_];   // 32 KB
    __shared__ unsigned long long tmin[256];
    __shared__ unsigned long long wmin[4];
    const int bi = blockIdx.x;
    const int b = bi >> 12;            // N_ = 4096
    const int i = bi & (N_ - 1);
    const int t = threadIdx.x;
    const float* cb = coors + (size_t)b * N_ * 3;
    const float xi = cb[i*3+0], yi = cb[i*3+1], zi = cb[i*3+2];

    unsigned long long mymin = ~0ULL;
    #pragma unroll
    for (int l = 0; l < N_/256; ++l) {
        const int j = t + l*256;
        const float dx = xi - cb[j*3+0];
        const float dy = yi - cb[j*3+1];
        const float dz = zi - cb[j*3+2];
        const float d = sqrtf(dx*dx + dy*dy + dz*dz);
        const unsigned long long key =
            ((unsigned long long)__float_as_uint(d) << 32) | (unsigned)j;
        keys[j] = key;
        mymin = ullmin2(mymin, key);
    }
    tmin[t] = mymin;
    __syncthreads();

    for (int r = 0; r < KNN_; ++r) {
        // wave-level reduce of the 256 per-thread minima
        unsigned long long v = tmin[t];
        #pragma unroll
        for (int off = 32; off; off >>= 1)
            v = ullmin2(v, __shfl_xor(v, off));
        if ((t & 63) == 0) wmin[t >> 6] = v;
        __syncthreads();
        const unsigned long long win =
            ullmin2(ullmin2(wmin[0], wmin[1]), ullmin2(wmin[2], wmin[3]));
        const int wj = (int)(win & 0xffffffffu);
        if (t == 0) nbhd[(size_t)bi * KNN_ + r] = wj;
        if (t == (wj & 255)) {            // owner of keys[wj] (wj mod 256 == t)
            keys[wj] = ~0ULL;
            unsigned long long mm = ~0ULL;
            #pragma unroll
            for (int l = 0; l < N_/256; ++l)
                mm = ullmin2(mm, keys[t + l*256]);
            tmin[t] = mm;
        }
        __syncthreads();
    }
}

// ---------------- generic f32 tiled GEMM: C = A(MxK) @ Bm(KxN) (+bias) ----------------
__global__ __launch_bounds__(256) void gemm_kernel(const float* __restrict__ A,
                                                   const float* __restrict__ Bm,
                                                   const float* __restrict__ bias,
                                                   float* __restrict__ C,
                                                   int M, int K, int Nn) {
    __shared__ float As[32*65];   // [k][m], padded
    __shared__ float Bs[32*64];   // [k][n]
    const int tx = threadIdx.x & 15, ty = threadIdx.x >> 4;
    const int row0 = blockIdx.y * 64, col0 = blockIdx.x * 64;
    float acc[4][4] = {};
    for (int k0 = 0; k0 < K; k0 += 32) {
        #pragma unroll
        for (int l = 0; l < 8; ++l) {
            const int idx = l*256 + threadIdx.x;
            const int r  = idx >> 5, c  = idx & 31;
            As[c*65 + r] = A[(size_t)(row0 + r) * K + k0 + c];
            const int r2 = idx >> 6, c2 = idx & 63;
            Bs[r2*64 + c2] = Bm[(size_t)(k0 + r2) * Nn + col0 + c2];
        }
        __syncthreads();
        #pragma unroll
        for (int kk = 0; kk < 32; ++kk) {
            float a[4], bb[4];
            #pragma unroll
            for (int m = 0; m < 4; ++m) a[m]  = As[kk*65 + ty*4 + m];
            #pragma unroll
            for (int n = 0; n < 4; ++n) bb[n] = Bs[kk*64 + tx*4 + n];
            #pragma unroll
            for (int m = 0; m < 4; ++m)
                #pragma unroll
                for (int n = 0; n < 4; ++n)
                    acc[m][n] += a[m] * bb[n];
        }
        __syncthreads();
    }
    #pragma unroll
    for (int m = 0; m < 4; ++m)
        #pragma unroll
        for (int n = 0; n < 4; ++n) {
            const int col = col0 + tx*4 + n;
            float v = acc[m][n];
            if (bias) v += bias[col];
            C[(size_t)(row0 + ty*4 + m) * Nn + col] = v;
        }
}

// ---------------- Kernel C: fused neighbor attention per (b,i) ----------------
// block = 256 threads: wave h = head, lane d = head-dim
__global__ __launch_bounds__(256) void attn_kernel(const float* __restrict__ qkv,
                                                   const float* __restrict__ coors,
                                                   const int* __restrict__ nbhd,
                                                   const float* __restrict__ w_c1,
                                                   const float* __restrict__ b_c1,
                                                   const float* __restrict__ w_c2,
                                                   const float* __restrict__ b_c2,
                                                   const float* __restrict__ ln_b,
                                                   float* __restrict__ out_pre,
                                                   float* __restrict__ coors_out) {
    __shared__ float vg[KNN_][INNER_];      // 32 KB rotated v
    __shared__ float qkl[KNN_][HEADS_];
    __shared__ float attnl[KNN_][HEADS_];
    __shared__ float coorw[KNN_];
    __shared__ float distl[KNN_];
    __shared__ float ul[KNN_][3];
    __shared__ int   njl[KNN_];

    const int bi = blockIdx.x;
    const int b = bi >> 12;
    const int i = bi & (N_ - 1);
    const int t = threadIdx.x;
    const int h = t >> 6;
    const int d = t & 63;
    const float* cb = coors + (size_t)b * N_ * 3;

    if (t < KNN_) {
        const int nj = nbhd[(size_t)bi * KNN_ + t];
        njl[t] = nj;
        const float dx = cb[i*3+0] - cb[nj*3+0];
        const float dy = cb[i*3+1] - cb[nj*3+1];
        const float dz = cb[i*3+2] - cb[nj*3+2];
        const float dist = sqrtf(dx*dx + dy*dy + dz*dz);
        distl[t] = dist;
        const float den = fmaxf(dist, 1e-8f);
        ul[t][0] = dx / den; ul[t][1] = dy / den; ul[t][2] = dz / den;
    }
    const float qv = qkv[(size_t)bi * QKVW_ + h*DH_ + d];   // q rotary == identity
    const float invf = (d < 32) ? powf(10000.0f, -(float)(d >> 1) / 16.0f) : 0.0f;
    __syncthreads();

    for (int j = 0; j < KNN_; ++j) {
        const int nj = njl[j];
        const float* base = qkv + (size_t)(b * N_ + nj) * QKVW_;
        float kr = base[INNER_   + h*DH_ + d];
        float vr = base[2*INNER_ + h*DH_ + d];
        const float kp = __shfl_xor(kr, 1);
        const float vp = __shfl_xor(vr, 1);
        if (d < 32) {
            const float f  = distl[j] * 100.0f * invf;
            const float cf = cosf(f), sf = sinf(f);
            if (d & 1) { kr = kr*cf + kp*sf; vr = vr*cf + vp*sf; }
            else       { kr = kr*cf - kp*sf; vr = vr*cf - vp*sf; }
        }
        vg[j][h*DH_ + d] = vr;
        float p = qv * kr;
        #pragma unroll
        for (int off = 32; off; off >>= 1) p += __shfl_xor(p, off);
        if (d == 0) qkl[j][h] = p * 0.125f;    // * dh^-0.5
    }
    __syncthreads();

    // softmax over j, per head (wave h handles head h)
    const float x = (d < KNN_) ? qkl[d][h] : -INFINITY;
    float mx = x;
    #pragma unroll
    for (int off = 32; off; off >>= 1) mx = fmaxf(mx, __shfl_xor(mx, off));
    const float e = expf(x - mx);              // lanes >= 32 contribute 0
    float s = e;
    #pragma unroll
    for (int off = 32; off; off >>= 1) s += __shfl_xor(s, off);
    if (d < KNN_) attnl[d][h] = e / s;

    // coordinate-weight MLP (4 -> 16 -> 1, exact gelu), lanes 0..31 of wave 0
    if (t < KNN_) {
        const float q0 = qkl[t][0], q1 = qkl[t][1], q2 = qkl[t][2], q3 = qkl[t][3];
        float cw = b_c2[0];
        #pragma unroll
        for (int mh = 0; mh < 16; ++mh) {
            const float hv = q0*w_c1[0*16+mh] + q1*w_c1[1*16+mh]
                           + q2*w_c1[2*16+mh] + q3*w_c1[3*16+mh] + b_c1[mh];
            const float g = 0.5f * hv * (1.0f + erff(hv * 0.70710678118654752440f));
            cw += g * w_c2[mh];
        }
        coorw[t] = cw;
    }
    __syncthreads();

    float o = 0.0f;
    #pragma unroll
    for (int j = 0; j < KNN_; ++j) o += attnl[j][h] * vg[j][h*DH_ + d];
    out_pre[(size_t)bi * INNER_ + h*DH_ + d] = o;

    if (t < 3) {
        float acc = 0.0f;
        #pragma unroll
        for (int j = 0; j < KNN_; ++j) acc += coorw[j] * ul[j][t];
        coors_out[(size_t)bi * 3 + t] = acc * ln_b[0];
    }
}

extern "C" void kernel_launch(void* const* d_in, const int* in_sizes, int n_in,
                              void* d_out, int out_size, void* d_ws, size_t ws_size,
                              hipStream_t stream) {
    (void)in_sizes; (void)n_in; (void)out_size; (void)ws_size;
    const float* feats = (const float*)d_in[0];
    const float* coors = (const float*)d_in[1];
    const float* w_qkv = (const float*)d_in[2];
    const float* w_out = (const float*)d_in[3];
    const float* b_out = (const float*)d_in[4];
    const float* w_c1  = (const float*)d_in[5];
    const float* b_c1  = (const float*)d_in[6];
    const float* w_c2  = (const float*)d_in[7];
    const float* b_c2  = (const float*)d_in[8];
    const float* ln_b  = (const float*)d_in[10];   // ln_g (d_in[9]) is dead

    const int M = B_ * N_;                          // 8192
    float* ws      = (float*)d_ws;
    float* qkv     = ws;                            // 8192*768 floats
    int*   nbhd    = (int*)(ws + (size_t)M * QKVW_);// 8192*32 ints
    float* out_pre = ws + (size_t)M * QKVW_ + (size_t)M * KNN_; // 8192*256 floats

    float* out_main  = (float*)d_out;               // 8192*256
    float* out_coors = out_main + (size_t)M * DIM_; // 8192*3

    // qkv = feats @ w_qkv   (M x 256) @ (256 x 768)
    gemm_kernel<<<dim3(QKVW_/64, M/64), 256, 0, stream>>>(feats, w_qkv, nullptr, qkv,
                                                          M, DIM_, QKVW_);
    // exact top-32 neighbors
    knn_kernel<<<M, 256, 0, stream>>>(coors, nbhd);
    // fused neighbor attention + coordinate path
    attn_kernel<<<M, 256, 0, stream>>>(qkv, coors, nbhd, w_c1, b_c1, w_c2, b_c2, ln_b,
                                       out_pre, out_coors);
    // out = out_pre @ w_out + b_out   (M x 256) @ (256 x 256)
    gemm_kernel<<<dim3(DIM_/64, M/64), 256, 0, stream>>>(out_pre, w_out, b_out, out_main,
                                                         M, DIM_, DIM_);
}

// Round 3
// 416.855 us; speedup vs baseline: 1.3294x; 1.3294x over previous
//
#include <hip/hip_runtime.h>
#include <math.h>

#define B_ 2
#define N_ 4096
#define DIM_ 256
#define HEADS_ 4
#define DH_ 64
#define KNN_ 32
#define INNER_ 256       // HEADS*DH
#define QKVW_ 768        // 3*INNER
#define HB_ 512          // histogram bins
#define CAND_ 512        // boundary-bin candidate cap

static __device__ __forceinline__ unsigned long long ullmin2(unsigned long long a, unsigned long long b) {
    return a < b ? a : b;
}

// ---------------- Kernel A: exact KNN via histogram select ----------------
// One block per query (b,i). Exact same selection as lax.top_k(-dist, 32):
// key = (f32 bits of dist, index); all per-neighbor reductions downstream are
// permutation-invariant, so output order within the 32 is free.
__global__ __launch_bounds__(256) void knn_kernel(const float* __restrict__ coors,
                                                  int* __restrict__ nbhd) {
    __shared__ float dists[N_];                 // 16 KB
    __shared__ int   hist[HB_];                 // 2 KB
    __shared__ unsigned long long cand[CAND_];  // 4 KB
    __shared__ float tminf[256];
    __shared__ float Msh;
    __shared__ int   bsh, clsh, candcnt, outcnt;

    const int bi = blockIdx.x;
    const int b = bi >> 12;            // N_ = 4096
    const int i = bi & (N_ - 1);
    const int t = threadIdx.x;
    const float* cb = coors + (size_t)b * N_ * 3;
    const float xi = cb[i*3+0], yi = cb[i*3+1], zi = cb[i*3+2];

    // phase 1: all distances + per-thread min
    float mymin = INFINITY;
    #pragma unroll
    for (int l = 0; l < N_/256; ++l) {
        const int j = t + l*256;
        const float dx = xi - cb[j*3+0];
        const float dy = yi - cb[j*3+1];
        const float dz = zi - cb[j*3+2];
        const float d = sqrtf(dx*dx + dy*dy + dz*dz);
        dists[j] = d;
        mymin = fminf(mymin, d);
    }
    tminf[t] = mymin;
    hist[t] = 0; hist[t + 256] = 0;
    if (t == 0) { candcnt = 0; outcnt = 0; }
    __syncthreads();

    // M = max over threads of per-thread min  (provable upper bound on d32:
    // d32 <= 32nd smallest of the 256 minima <= M)
    if (t < 64) {
        float m4 = fmaxf(fmaxf(tminf[t], tminf[t+64]), fmaxf(tminf[t+128], tminf[t+192]));
        #pragma unroll
        for (int off = 32; off; off >>= 1) m4 = fmaxf(m4, __shfl_xor(m4, off));
        if (t == 0) Msh = fmaxf(m4, 1e-20f);
    }
    __syncthreads();

    const float scale = (float)(HB_ - 1) / Msh;

    // phase 2: histogram
    #pragma unroll
    for (int l = 0; l < N_/256; ++l) {
        const int j = t + l*256;
        const int bin = (int)fminf(dists[j] * scale, (float)(HB_ - 1));
        atomicAdd(&hist[bin], 1);
    }
    __syncthreads();

    // phase 3: wave 0 finds boundary bin b and count-below c_less
    if (t < 64) {
        int s = 0;
        #pragma unroll
        for (int k = 0; k < HB_/64; ++k) s += hist[t*(HB_/64) + k];
        int inc = s;
        #pragma unroll
        for (int off = 1; off < 64; off <<= 1) {
            const int v = __shfl_up(inc, off);
            if (t >= off) inc += v;
        }
        const int excl = inc - s;
        if (excl < KNN_ && inc >= KNN_) {       // unique crossing lane
            int cum = excl;
            #pragma unroll
            for (int k = 0; k < HB_/64; ++k) {
                const int c = hist[t*(HB_/64) + k];
                if (cum + c >= KNN_) { bsh = t*(HB_/64) + k; clsh = cum; break; }
                cum += c;
            }
        }
    }
    __syncthreads();

    const int bbin = bsh, c_less = clsh;

    // phase 4: accepted (bin < b) -> emit; boundary (bin == b) -> candidates
    #pragma unroll
    for (int l = 0; l < N_/256; ++l) {
        const int j = t + l*256;
        const float d = dists[j];
        const int bin = (int)fminf(d * scale, (float)(HB_ - 1));
        if (bin < bbin) {
            const int slot = atomicAdd(&outcnt, 1);
            nbhd[(size_t)bi * KNN_ + slot] = j;
        } else if (bin == bbin) {
            const int c = atomicAdd(&candcnt, 1);
            if (c < CAND_) {
                cand[c] = ((unsigned long long)__float_as_uint(d) << 32) | (unsigned)j;
            }
        }
    }
    __syncthreads();

    // phase 5: pick remaining m = 32 - c_less from boundary bin by exact key
    const int m = KNN_ - c_less;
    const int e = candcnt;
    if (e <= CAND_) {
        if (t < 64) {
            for (int r = 0; r < m; ++r) {
                unsigned long long v = ~0ULL;
                for (int idx = t; idx < e; idx += 64) v = ullmin2(v, cand[idx]);
                #pragma unroll
                for (int off = 32; off; off >>= 1) v = ullmin2(v, __shfl_xor(v, off));
                if (t == 0) nbhd[(size_t)bi * KNN_ + c_less + r] = (int)(v & 0xffffffffu);
                for (int idx = t; idx < e; idx += 64)
                    if (cand[idx] == v) cand[idx] = ~0ULL;
            }
        }
    } else if (t == 0) {
        // degenerate fallback (massively tied distances) — correct, slow, unused
        for (int r = 0; r < m; ++r) {
            unsigned long long best = ~0ULL;
            for (int j = 0; j < N_; ++j) {
                const float d = dists[j];
                const int bin = (int)fminf(d * scale, (float)(HB_ - 1));
                if (bin == bbin) {
                    const unsigned long long key =
                        ((unsigned long long)__float_as_uint(d) << 32) | (unsigned)j;
                    best = ullmin2(best, key);
                }
            }
            const int wj = (int)(best & 0xffffffffu);
            nbhd[(size_t)bi * KNN_ + c_less + r] = wj;
            dists[wj] = INFINITY;
        }
    }
}

// ---------------- generic f32 tiled GEMM: C = A(MxK) @ Bm(KxN) (+bias) ----------------
__global__ __launch_bounds__(256) void gemm_kernel(const float* __restrict__ A,
                                                   const float* __restrict__ Bm,
                                                   const float* __restrict__ bias,
                                                   float* __restrict__ C,
                                                   int M, int K, int Nn) {
    __shared__ float As[32*65];   // [k][m], padded
    __shared__ float Bs[32*64];   // [k][n]
    const int tx = threadIdx.x & 15, ty = threadIdx.x >> 4;
    const int row0 = blockIdx.y * 64, col0 = blockIdx.x * 64;
    float acc[4][4] = {};
    for (int k0 = 0; k0 < K; k0 += 32) {
        #pragma unroll
        for (int l = 0; l < 8; ++l) {
            const int idx = l*256 + threadIdx.x;
            const int r  = idx >> 5, c  = idx & 31;
            As[c*65 + r] = A[(size_t)(row0 + r) * K + k0 + c];
            const int r2 = idx >> 6, c2 = idx & 63;
            Bs[r2*64 + c2] = Bm[(size_t)(k0 + r2) * Nn + col0 + c2];
        }
        __syncthreads();
        #pragma unroll
        for (int kk = 0; kk < 32; ++kk) {
            float a[4], bb[4];
            #pragma unroll
            for (int m = 0; m < 4; ++m) a[m]  = As[kk*65 + ty*4 + m];
            #pragma unroll
            for (int n = 0; n < 4; ++n) bb[n] = Bs[kk*64 + tx*4 + n];
            #pragma unroll
            for (int m = 0; m < 4; ++m)
                #pragma unroll
                for (int n = 0; n < 4; ++n)
                    acc[m][n] += a[m] * bb[n];
        }
        __syncthreads();
    }
    #pragma unroll
    for (int m = 0; m < 4; ++m)
        #pragma unroll
        for (int n = 0; n < 4; ++n) {
            const int col = col0 + tx*4 + n;
            float v = acc[m][n];
            if (bias) v += bias[col];
            C[(size_t)(row0 + ty*4 + m) * Nn + col] = v;
        }
}

// ---------------- Kernel C: fused neighbor attention per (b,i) ----------------
// block = 256 threads: wave h = head, lane d = head-dim
__global__ __launch_bounds__(256) void attn_kernel(const float* __restrict__ qkv,
                                                   const float* __restrict__ coors,
                                                   const int* __restrict__ nbhd,
                                                   const float* __restrict__ w_c1,
                                                   const float* __restrict__ b_c1,
                                                   const float* __restrict__ w_c2,
                                                   const float* __restrict__ b_c2,
                                                   const float* __restrict__ ln_b,
                                                   float* __restrict__ out_pre,
                                                   float* __restrict__ coors_out) {
    __shared__ float vg[KNN_][INNER_];      // 32 KB rotated v
    __shared__ float qkl[KNN_][HEADS_];
    __shared__ float attnl[KNN_][HEADS_];
    __shared__ float coorw[KNN_];
    __shared__ float distl[KNN_];
    __shared__ float ul[KNN_][3];
    __shared__ int   njl[KNN_];

    const int bi = blockIdx.x;
    const int b = bi >> 12;
    const int i = bi & (N_ - 1);
    const int t = threadIdx.x;
    const int h = t >> 6;
    const int d = t & 63;
    const float* cb = coors + (size_t)b * N_ * 3;

    if (t < KNN_) {
        const int nj = nbhd[(size_t)bi * KNN_ + t];
        njl[t] = nj;
        const float dx = cb[i*3+0] - cb[nj*3+0];
        const float dy = cb[i*3+1] - cb[nj*3+1];
        const float dz = cb[i*3+2] - cb[nj*3+2];
        const float dist = sqrtf(dx*dx + dy*dy + dz*dz);
        distl[t] = dist;
        const float den = fmaxf(dist, 1e-8f);
        ul[t][0] = dx / den; ul[t][1] = dy / den; ul[t][2] = dz / den;
    }
    const float qv = qkv[(size_t)bi * QKVW_ + h*DH_ + d];   // q rotary == identity
    const float invf = (d < 32) ? powf(10000.0f, -(float)(d >> 1) / 16.0f) : 0.0f;
    __syncthreads();

    for (int j = 0; j < KNN_; ++j) {
        const int nj = njl[j];
        const float* base = qkv + (size_t)(b * N_ + nj) * QKVW_;
        float kr = base[INNER_   + h*DH_ + d];
        float vr = base[2*INNER_ + h*DH_ + d];
        const float kp = __shfl_xor(kr, 1);
        const float vp = __shfl_xor(vr, 1);
        if (d < 32) {
            const float f  = distl[j] * 100.0f * invf;
            const float cf = cosf(f), sf = sinf(f);
            if (d & 1) { kr = kr*cf + kp*sf; vr = vr*cf + vp*sf; }
            else       { kr = kr*cf - kp*sf; vr = vr*cf - vp*sf; }
        }
        vg[j][h*DH_ + d] = vr;
        float p = qv * kr;
        #pragma unroll
        for (int off = 32; off; off >>= 1) p += __shfl_xor(p, off);
        if (d == 0) qkl[j][h] = p * 0.125f;    // * dh^-0.5
    }
    __syncthreads();

    // softmax over j, per head (wave h handles head h)
    const float x = (d < KNN_) ? qkl[d][h] : -INFINITY;
    float mx = x;
    #pragma unroll
    for (int off = 32; off; off >>= 1) mx = fmaxf(mx, __shfl_xor(mx, off));
    const float e = expf(x - mx);              // lanes >= 32 contribute 0
    float s = e;
    #pragma unroll
    for (int off = 32; off; off >>= 1) s += __shfl_xor(s, off);
    if (d < KNN_) attnl[d][h] = e / s;

    // coordinate-weight MLP (4 -> 16 -> 1, exact gelu), lanes 0..31 of wave 0
    if (t < KNN_) {
        const float q0 = qkl[t][0], q1 = qkl[t][1], q2 = qkl[t][2], q3 = qkl[t][3];
        float cw = b_c2[0];
        #pragma unroll
        for (int mh = 0; mh < 16; ++mh) {
            const float hv = q0*w_c1[0*16+mh] + q1*w_c1[1*16+mh]
                           + q2*w_c1[2*16+mh] + q3*w_c1[3*16+mh] + b_c1[mh];
            const float g = 0.5f * hv * (1.0f + erff(hv * 0.70710678118654752440f));
            cw += g * w_c2[mh];
        }
        coorw[t] = cw;
    }
    __syncthreads();

    float o = 0.0f;
    #pragma unroll
    for (int j = 0; j < KNN_; ++j) o += attnl[j][h] * vg[j][h*DH_ + d];
    out_pre[(size_t)bi * INNER_ + h*DH_ + d] = o;

    if (t < 3) {
        float acc = 0.0f;
        #pragma unroll
        for (int j = 0; j < KNN_; ++j) acc += coorw[j] * ul[j][t];
        coors_out[(size_t)bi * 3 + t] = acc * ln_b[0];
    }
}

extern "C" void kernel_launch(void* const* d_in, const int* in_sizes, int n_in,
                              void* d_out, int out_size, void* d_ws, size_t ws_size,
                              hipStream_t stream) {
    (void)in_sizes; (void)n_in; (void)out_size; (void)ws_size;
    const float* feats = (const float*)d_in[0];
    const float* coors = (const float*)d_in[1];
    const float* w_qkv = (const float*)d_in[2];
    const float* w_out = (const float*)d_in[3];
    const float* b_out = (const float*)d_in[4];
    const float* w_c1  = (const float*)d_in[5];
    const float* b_c1  = (const float*)d_in[6];
    const float* w_c2  = (const float*)d_in[7];
    const float* b_c2  = (const float*)d_in[8];
    const float* ln_b  = (const float*)d_in[10];   // ln_g (d_in[9]) is dead

    const int M = B_ * N_;                          // 8192
    float* ws      = (float*)d_ws;
    float* qkv     = ws;                            // 8192*768 floats
    int*   nbhd    = (int*)(ws + (size_t)M * QKVW_);// 8192*32 ints
    float* out_pre = ws + (size_t)M * QKVW_ + (size_t)M * KNN_; // 8192*256 floats

    float* out_main  = (float*)d_out;               // 8192*256
    float* out_coors = out_main + (size_t)M * DIM_; // 8192*3

    // qkv = feats @ w_qkv   (M x 256) @ (256 x 768)
    gemm_kernel<<<dim3(QKVW_/64, M/64), 256, 0, stream>>>(feats, w_qkv, nullptr, qkv,
                                                          M, DIM_, QKVW_);
    // exact top-32 neighbors
    knn_kernel<<<M, 256, 0, stream>>>(coors, nbhd);
    // fused neighbor attention + coordinate path
    attn_kernel<<<M, 256, 0, stream>>>(qkv, coors, nbhd, w_c1, b_c1, w_c2, b_c2, ln_b,
                                       out_pre, out_coors);
    // out = out_pre @ w_out + b_out   (M x 256) @ (256 x 256)
    gemm_kernel<<<dim3(DIM_/64, M/64), 256, 0, stream>>>(out_pre, w_out, b_out, out_main,
                                                         M, DIM_, DIM_);
}

// Round 4
// 261.127 us; speedup vs baseline: 2.1221x; 1.5964x over previous
//
#include <hip/hip_runtime.h>
#include <math.h>

#define B_ 2
#define N_ 4096
#define DIM_ 256
#define HEADS_ 4
#define DH_ 64
#define KNN_ 32
#define INNER_ 256       // HEADS*DH
#define QKVW_ 768        // 3*INNER
#define HB_ 512          // histogram bins
#define CAND_ 512        // boundary-bin candidate cap
#define VROW_ 260        // padded vg row (floats)

static __device__ __forceinline__ unsigned long long ullmin2(unsigned long long a, unsigned long long b) {
    return a < b ? a : b;
}

// ---------------- Kernel A: exact KNN via histogram select ----------------
__global__ __launch_bounds__(256) void knn_kernel(const float* __restrict__ coors,
                                                  int* __restrict__ nbhd) {
    __shared__ float dists[N_];                 // 16 KB
    __shared__ int   hist[HB_];                 // 2 KB
    __shared__ unsigned long long cand[CAND_];  // 4 KB
    __shared__ float tminf[256];
    __shared__ float Msh;
    __shared__ int   bsh, clsh, candcnt, outcnt;

    const int bi = blockIdx.x;
    const int b = bi >> 12;            // N_ = 4096
    const int i = bi & (N_ - 1);
    const int t = threadIdx.x;
    const float* cb = coors + (size_t)b * N_ * 3;
    const float xi = cb[i*3+0], yi = cb[i*3+1], zi = cb[i*3+2];

    float mymin = INFINITY;
    #pragma unroll
    for (int l = 0; l < N_/256; ++l) {
        const int j = t + l*256;
        const float dx = xi - cb[j*3+0];
        const float dy = yi - cb[j*3+1];
        const float dz = zi - cb[j*3+2];
        const float d = sqrtf(dx*dx + dy*dy + dz*dz);
        dists[j] = d;
        mymin = fminf(mymin, d);
    }
    tminf[t] = mymin;
    hist[t] = 0; hist[t + 256] = 0;
    if (t == 0) { candcnt = 0; outcnt = 0; }
    __syncthreads();

    if (t < 64) {
        float m4 = fmaxf(fmaxf(tminf[t], tminf[t+64]), fmaxf(tminf[t+128], tminf[t+192]));
        #pragma unroll
        for (int off = 32; off; off >>= 1) m4 = fmaxf(m4, __shfl_xor(m4, off));
        if (t == 0) Msh = fmaxf(m4, 1e-20f);
    }
    __syncthreads();

    const float scale = (float)(HB_ - 1) / Msh;

    #pragma unroll
    for (int l = 0; l < N_/256; ++l) {
        const int j = t + l*256;
        const int bin = (int)fminf(dists[j] * scale, (float)(HB_ - 1));
        atomicAdd(&hist[bin], 1);
    }
    __syncthreads();

    if (t < 64) {
        int s = 0;
        #pragma unroll
        for (int k = 0; k < HB_/64; ++k) s += hist[t*(HB_/64) + k];
        int inc = s;
        #pragma unroll
        for (int off = 1; off < 64; off <<= 1) {
            const int v = __shfl_up(inc, off);
            if (t >= off) inc += v;
        }
        const int excl = inc - s;
        if (excl < KNN_ && inc >= KNN_) {
            int cum = excl;
            #pragma unroll
            for (int k = 0; k < HB_/64; ++k) {
                const int c = hist[t*(HB_/64) + k];
                if (cum + c >= KNN_) { bsh = t*(HB_/64) + k; clsh = cum; break; }
                cum += c;
            }
        }
    }
    __syncthreads();

    const int bbin = bsh, c_less = clsh;

    #pragma unroll
    for (int l = 0; l < N_/256; ++l) {
        const int j = t + l*256;
        const float d = dists[j];
        const int bin = (int)fminf(d * scale, (float)(HB_ - 1));
        if (bin < bbin) {
            const int slot = atomicAdd(&outcnt, 1);
            nbhd[(size_t)bi * KNN_ + slot] = j;
        } else if (bin == bbin) {
            const int c = atomicAdd(&candcnt, 1);
            if (c < CAND_) {
                cand[c] = ((unsigned long long)__float_as_uint(d) << 32) | (unsigned)j;
            }
        }
    }
    __syncthreads();

    const int m = KNN_ - c_less;
    const int e = candcnt;
    if (e <= CAND_) {
        if (t < 64) {
            for (int r = 0; r < m; ++r) {
                unsigned long long v = ~0ULL;
                for (int idx = t; idx < e; idx += 64) v = ullmin2(v, cand[idx]);
                #pragma unroll
                for (int off = 32; off; off >>= 1) v = ullmin2(v, __shfl_xor(v, off));
                if (t == 0) nbhd[(size_t)bi * KNN_ + c_less + r] = (int)(v & 0xffffffffu);
                for (int idx = t; idx < e; idx += 64)
                    if (cand[idx] == v) cand[idx] = ~0ULL;
            }
        }
    } else if (t == 0) {
        for (int r = 0; r < m; ++r) {
            unsigned long long best = ~0ULL;
            for (int j = 0; j < N_; ++j) {
                const float d = dists[j];
                const int bin = (int)fminf(d * scale, (float)(HB_ - 1));
                if (bin == bbin) {
                    const unsigned long long key =
                        ((unsigned long long)__float_as_uint(d) << 32) | (unsigned)j;
                    best = ullmin2(best, key);
                }
            }
            const int wj = (int)(best & 0xffffffffu);
            nbhd[(size_t)bi * KNN_ + c_less + r] = wj;
            dists[wj] = INFINITY;
        }
    }
}

// ---------------- generic f32 tiled GEMM: C = A(MxK) @ Bm(KxN) (+bias) ----------------
__global__ __launch_bounds__(256) void gemm_kernel(const float* __restrict__ A,
                                                   const float* __restrict__ Bm,
                                                   const float* __restrict__ bias,
                                                   float* __restrict__ C,
                                                   int M, int K, int Nn) {
    __shared__ float As[32*65];   // [k][m], padded
    __shared__ float Bs[32*64];   // [k][n]
    const int tx = threadIdx.x & 15, ty = threadIdx.x >> 4;
    const int row0 = blockIdx.y * 64, col0 = blockIdx.x * 64;
    float acc[4][4] = {};
    for (int k0 = 0; k0 < K; k0 += 32) {
        #pragma unroll
        for (int l = 0; l < 8; ++l) {
            const int idx = l*256 + threadIdx.x;
            const int r  = idx >> 5, c  = idx & 31;
            As[c*65 + r] = A[(size_t)(row0 + r) * K + k0 + c];
            const int r2 = idx >> 6, c2 = idx & 63;
            Bs[r2*64 + c2] = Bm[(size_t)(k0 + r2) * Nn + col0 + c2];
        }
        __syncthreads();
        #pragma unroll
        for (int kk = 0; kk < 32; ++kk) {
            float a[4], bb[4];
            #pragma unroll
            for (int m = 0; m < 4; ++m) a[m]  = As[kk*65 + ty*4 + m];
            #pragma unroll
            for (int n = 0; n < 4; ++n) bb[n] = Bs[kk*64 + tx*4 + n];
            #pragma unroll
            for (int m = 0; m < 4; ++m)
                #pragma unroll
                for (int n = 0; n < 4; ++n)
                    acc[m][n] += a[m] * bb[n];
        }
        __syncthreads();
    }
    #pragma unroll
    for (int m = 0; m < 4; ++m)
        #pragma unroll
        for (int n = 0; n < 4; ++n) {
            const int col = col0 + tx*4 + n;
            float v = acc[m][n];
            if (bias) v += bias[col];
            C[(size_t)(row0 + ty*4 + m) * Nn + col] = v;
        }
}

// ---------------- Kernel C: fused neighbor attention per (b,i) ----------------
// 256 threads = 4 waves. Gather: wave w owns neighbors j = w*8..w*8+7; lane l
// owns dims [4l..4l+3] of the 256-wide k/v rows (head h = l>>4). Rotary pairs
// are within the float4 -> no cross-lane ops. k is consumed in-register by the
// qk dot (4 FMA + 4 shfl_xor over the 16-lane head group); only rotated v is
// staged to LDS.
__global__ __launch_bounds__(256) void attn_kernel(const float* __restrict__ qkv,
                                                   const float* __restrict__ coors,
                                                   const int* __restrict__ nbhd,
                                                   const float* __restrict__ w_c1,
                                                   const float* __restrict__ b_c1,
                                                   const float* __restrict__ w_c2,
                                                   const float* __restrict__ b_c2,
                                                   const float* __restrict__ ln_b,
                                                   float* __restrict__ out_pre,
                                                   float* __restrict__ coors_out) {
    __shared__ float vg[KNN_ * VROW_];      // 32.5 KB rotated v, padded rows
    __shared__ float qkl[KNN_][HEADS_];
    __shared__ float attnl[KNN_][HEADS_];
    __shared__ float coorw[KNN_];
    __shared__ float distl[KNN_];           // holds dist*100
    __shared__ float ul[KNN_][3];
    __shared__ int   njl[KNN_];

    const int bi = blockIdx.x;
    const int b = bi >> 12;
    const int i = bi & (N_ - 1);
    const int t = threadIdx.x;
    const int w = t >> 6;                   // wave id
    const int l = t & 63;                   // lane
    const float* cb = coors + (size_t)b * N_ * 3;

    if (t < KNN_) {
        const int nj = nbhd[(size_t)bi * KNN_ + t];
        njl[t] = nj;
        const float dx = cb[i*3+0] - cb[nj*3+0];
        const float dy = cb[i*3+1] - cb[nj*3+1];
        const float dz = cb[i*3+2] - cb[nj*3+2];
        const float dist = sqrtf(dx*dx + dy*dy + dz*dz);
        distl[t] = dist * 100.0f;
        const float den = fmaxf(dist, 1e-8f);
        ul[t][0] = dx / den; ul[t][1] = dy / den; ul[t][2] = dz / den;
    }

    // q fragment (rotary on q is identity): dims [4l..4l+3] of row bi
    const float4 q4 = *(const float4*)(qkv + (size_t)bi * QKVW_ + 4*l);
    // rotary constants: dims-in-head dd = 4*(l&15); rotate iff dd < 32
    const int li = l & 15;
    const bool rot = li < 8;
    const float invf0 = exp2f(-(float)(2*li    ) * 0.8304820237218407f);  // log2(1e4)/16
    const float invf1 = exp2f(-(float)(2*li + 1) * 0.8304820237218407f);
    __syncthreads();

    #pragma unroll 2
    for (int jj = 0; jj < 8; ++jj) {
        const int j = w*8 + jj;
        const int nj = njl[j];
        const float* base = qkv + (size_t)(b * N_ + nj) * QKVW_;
        float4 k4 = *(const float4*)(base + INNER_   + 4*l);
        float4 v4 = *(const float4*)(base + 2*INNER_ + 4*l);
        if (rot) {
            const float d100 = distl[j];
            float s0, c0, s1, c1;
            sincosf(d100 * invf0, &s0, &c0);
            sincosf(d100 * invf1, &s1, &c1);
            float x;
            x = k4.x; k4.x = x*c0 - k4.y*s0; k4.y = k4.y*c0 + x*s0;
            x = k4.z; k4.z = x*c1 - k4.w*s1; k4.w = k4.w*c1 + x*s1;
            x = v4.x; v4.x = x*c0 - v4.y*s0; v4.y = v4.y*c0 + x*s0;
            x = v4.z; v4.z = x*c1 - v4.w*s1; v4.w = v4.w*c1 + x*s1;
        }
        *(float4*)&vg[j * VROW_ + 4*l] = v4;
        float p = q4.x*k4.x + q4.y*k4.y + q4.z*k4.z + q4.w*k4.w;
        p += __shfl_xor(p, 1);
        p += __shfl_xor(p, 2);
        p += __shfl_xor(p, 4);
        p += __shfl_xor(p, 8);
        if (li == 0) qkl[j][l >> 4] = p * 0.125f;   // * dh^-0.5
    }
    __syncthreads();

    // softmax over j, per head (wave h = w handles head h)
    {
        const int d = l;
        const float x = (d < KNN_) ? qkl[d][w] : -INFINITY;
        float mx = x;
        #pragma unroll
        for (int off = 32; off; off >>= 1) mx = fmaxf(mx, __shfl_xor(mx, off));
        const float e = expf(x - mx);
        float s = e;
        #pragma unroll
        for (int off = 32; off; off >>= 1) s += __shfl_xor(s, off);
        if (d < KNN_) attnl[d][w] = e / s;
    }

    // coordinate-weight MLP (4 -> 16 -> 1, exact gelu), lanes 0..31 of wave 0
    if (t < KNN_) {
        const float q0 = qkl[t][0], q1 = qkl[t][1], q2 = qkl[t][2], q3 = qkl[t][3];
        float cw = b_c2[0];
        #pragma unroll
        for (int mh = 0; mh < 16; ++mh) {
            const float hv = q0*w_c1[0*16+mh] + q1*w_c1[1*16+mh]
                           + q2*w_c1[2*16+mh] + q3*w_c1[3*16+mh] + b_c1[mh];
            const float g = 0.5f * hv * (1.0f + erff(hv * 0.70710678118654752440f));
            cw += g * w_c2[mh];
        }
        coorw[t] = cw;
    }
    __syncthreads();

    // out = sum_j attn[j][h] * vg[j][h*64+d]   (thread t = h*64+d)
    float o = 0.0f;
    #pragma unroll
    for (int j = 0; j < KNN_; ++j) o += attnl[j][w] * vg[j * VROW_ + t];
    out_pre[(size_t)bi * INNER_ + t] = o;

    if (t < 3) {
        float acc = 0.0f;
        #pragma unroll
        for (int j = 0; j < KNN_; ++j) acc += coorw[j] * ul[j][t];
        coors_out[(size_t)bi * 3 + t] = acc * ln_b[0];
    }
}

extern "C" void kernel_launch(void* const* d_in, const int* in_sizes, int n_in,
                              void* d_out, int out_size, void* d_ws, size_t ws_size,
                              hipStream_t stream) {
    (void)in_sizes; (void)n_in; (void)out_size; (void)ws_size;
    const float* feats = (const float*)d_in[0];
    const float* coors = (const float*)d_in[1];
    const float* w_qkv = (const float*)d_in[2];
    const float* w_out = (const float*)d_in[3];
    const float* b_out = (const float*)d_in[4];
    const float* w_c1  = (const float*)d_in[5];
    const float* b_c1  = (const float*)d_in[6];
    const float* w_c2  = (const float*)d_in[7];
    const float* b_c2  = (const float*)d_in[8];
    const float* ln_b  = (const float*)d_in[10];   // ln_g (d_in[9]) is dead

    const int M = B_ * N_;                          // 8192
    float* ws      = (float*)d_ws;
    float* qkv     = ws;                            // 8192*768 floats
    int*   nbhd    = (int*)(ws + (size_t)M * QKVW_);// 8192*32 ints
    float* out_pre = ws + (size_t)M * QKVW_ + (size_t)M * KNN_; // 8192*256 floats

    float* out_main  = (float*)d_out;               // 8192*256
    float* out_coors = out_main + (size_t)M * DIM_; // 8192*3

    gemm_kernel<<<dim3(QKVW_/64, M/64), 256, 0, stream>>>(feats, w_qkv, nullptr, qkv,
                                                          M, DIM_, QKVW_);
    knn_kernel<<<M, 256, 0, stream>>>(coors, nbhd);
    attn_kernel<<<M, 256, 0, stream>>>(qkv, coors, nbhd, w_c1, b_c1, w_c2, b_c2, ln_b,
                                       out_pre, out_coors);
    gemm_kernel<<<dim3(DIM_/64, M/64), 256, 0, stream>>>(out_pre, w_out, b_out, out_main,
                                                         M, DIM_, DIM_);
}

// Round 5
// 205.412 us; speedup vs baseline: 2.6977x; 1.2712x over previous
//
#include <hip/hip_runtime.h>
#include <math.h>

#define B_ 2
#define N_ 4096
#define DIM_ 256
#define HEADS_ 4
#define DH_ 64
#define KNN_ 32
#define INNER_ 256       // HEADS*DH
#define QKVW_ 768        // 3*INNER
#define HB_ 512          // histogram bins
#define CAND_ 512        // boundary-bin candidate cap
#define VROW_ 260        // padded vg row (floats)

static __device__ __forceinline__ unsigned long long ullmin2(unsigned long long a, unsigned long long b) {
    return a < b ? a : b;
}

// ---------------- Kernel A: exact KNN via histogram select ----------------
// Key insight: M = max over threads of per-thread min is an upper bound on
// d32 (>=256 distances are <= M), so all d > M are irrelevant — skip them in
// BOTH histogram and classify (identical predicate => consistent selection).
__global__ __launch_bounds__(256) void knn_kernel(const float* __restrict__ coors,
                                                  int* __restrict__ nbhd) {
    __shared__ float dists[N_];                 // 16 KB
    __shared__ int   hist[HB_];                 // 2 KB
    __shared__ unsigned long long cand[CAND_];  // 4 KB
    __shared__ float tminf[256];
    __shared__ float Msh;
    __shared__ int   bsh, clsh, candcnt, outcnt;

    const int bi = blockIdx.x;
    const int b = bi >> 12;            // N_ = 4096
    const int i = bi & (N_ - 1);
    const int t = threadIdx.x;
    const float* cb = coors + (size_t)b * N_ * 3;
    const float xi = cb[i*3+0], yi = cb[i*3+1], zi = cb[i*3+2];

    // phase 1: all distances + per-thread min
    float mymin = INFINITY;
    #pragma unroll
    for (int l = 0; l < N_/256; ++l) {
        const int j = t + l*256;
        const float dx = xi - cb[j*3+0];
        const float dy = yi - cb[j*3+1];
        const float dz = zi - cb[j*3+2];
        const float d = sqrtf(dx*dx + dy*dy + dz*dz);
        dists[j] = d;
        mymin = fminf(mymin, d);
    }
    tminf[t] = mymin;
    hist[t] = 0; hist[t + 256] = 0;
    if (t == 0) { candcnt = 0; outcnt = 0; }
    __syncthreads();

    if (t < 64) {
        float m4 = fmaxf(fmaxf(tminf[t], tminf[t+64]), fmaxf(tminf[t+128], tminf[t+192]));
        #pragma unroll
        for (int off = 32; off; off >>= 1) m4 = fmaxf(m4, __shfl_xor(m4, off));
        if (t == 0) Msh = fmaxf(m4, 1e-20f);
    }
    __syncthreads();

    const float Mv = Msh;
    const float scale = (float)(HB_ - 1) / Mv;

    // phase 2: histogram of RELEVANT distances only (d <= M)
    #pragma unroll
    for (int l = 0; l < N_/256; ++l) {
        const int j = t + l*256;
        const float d = dists[j];
        if (d <= Mv) {
            const int bin = (int)fminf(d * scale, (float)(HB_ - 1));
            atomicAdd(&hist[bin], 1);
        }
    }
    __syncthreads();

    // phase 3: wave 0 finds boundary bin b and count-below c_less
    if (t < 64) {
        int s = 0;
        #pragma unroll
        for (int k = 0; k < HB_/64; ++k) s += hist[t*(HB_/64) + k];
        int inc = s;
        #pragma unroll
        for (int off = 1; off < 64; off <<= 1) {
            const int v = __shfl_up(inc, off);
            if (t >= off) inc += v;
        }
        const int excl = inc - s;
        if (excl < KNN_ && inc >= KNN_) {       // unique crossing lane
            int cum = excl;
            #pragma unroll
            for (int k = 0; k < HB_/64; ++k) {
                const int c = hist[t*(HB_/64) + k];
                if (cum + c >= KNN_) { bsh = t*(HB_/64) + k; clsh = cum; break; }
                cum += c;
            }
        }
    }
    __syncthreads();

    const int bbin = bsh, c_less = clsh;

    // phase 4: accepted (bin < b) -> emit; boundary (bin == b) -> candidates
    #pragma unroll
    for (int l = 0; l < N_/256; ++l) {
        const int j = t + l*256;
        const float d = dists[j];
        if (d <= Mv) {
            const int bin = (int)fminf(d * scale, (float)(HB_ - 1));
            if (bin < bbin) {
                const int slot = atomicAdd(&outcnt, 1);
                nbhd[(size_t)bi * KNN_ + slot] = j;
            } else if (bin == bbin) {
                const int c = atomicAdd(&candcnt, 1);
                if (c < CAND_) {
                    cand[c] = ((unsigned long long)__float_as_uint(d) << 32) | (unsigned)j;
                }
            }
        }
    }
    __syncthreads();

    // phase 5: pick remaining m = 32 - c_less from boundary bin by exact key
    const int m = KNN_ - c_less;
    const int e = candcnt;
    if (e <= CAND_) {
        if (t < 64) {
            for (int r = 0; r < m; ++r) {
                unsigned long long v = ~0ULL;
                for (int idx = t; idx < e; idx += 64) v = ullmin2(v, cand[idx]);
                #pragma unroll
                for (int off = 32; off; off >>= 1) v = ullmin2(v, __shfl_xor(v, off));
                if (t == 0) nbhd[(size_t)bi * KNN_ + c_less + r] = (int)(v & 0xffffffffu);
                for (int idx = t; idx < e; idx += 64)
                    if (cand[idx] == v) cand[idx] = ~0ULL;
            }
        }
    } else if (t == 0) {
        // degenerate fallback (massively tied distances) — correct, slow, unused
        for (int r = 0; r < m; ++r) {
            unsigned long long best = ~0ULL;
            for (int j = 0; j < N_; ++j) {
                const float d = dists[j];
                if (d <= Mv) {
                    const int bin = (int)fminf(d * scale, (float)(HB_ - 1));
                    if (bin == bbin) {
                        const unsigned long long key =
                            ((unsigned long long)__float_as_uint(d) << 32) | (unsigned)j;
                        best = ullmin2(best, key);
                    }
                }
            }
            const int wj = (int)(best & 0xffffffffu);
            nbhd[(size_t)bi * KNN_ + c_less + r] = wj;
            dists[wj] = INFINITY;
        }
    }
}

// ---------------- generic f32 tiled GEMM: C = A(MxK) @ Bm(KxN) (+bias) ----------------
__global__ __launch_bounds__(256) void gemm_kernel(const float* __restrict__ A,
                                                   const float* __restrict__ Bm,
                                                   const float* __restrict__ bias,
                                                   float* __restrict__ C,
                                                   int M, int K, int Nn) {
    __shared__ float As[32*65];   // [k][m], padded
    __shared__ float Bs[32*64];   // [k][n]
    const int tx = threadIdx.x & 15, ty = threadIdx.x >> 4;
    const int row0 = blockIdx.y * 64, col0 = blockIdx.x * 64;
    float acc[4][4] = {};
    for (int k0 = 0; k0 < K; k0 += 32) {
        #pragma unroll
        for (int l = 0; l < 8; ++l) {
            const int idx = l*256 + threadIdx.x;
            const int r  = idx >> 5, c  = idx & 31;
            As[c*65 + r] = A[(size_t)(row0 + r) * K + k0 + c];
            const int r2 = idx >> 6, c2 = idx & 63;
            Bs[r2*64 + c2] = Bm[(size_t)(k0 + r2) * Nn + col0 + c2];
        }
        __syncthreads();
        #pragma unroll
        for (int kk = 0; kk < 32; ++kk) {
            float a[4], bb[4];
            #pragma unroll
            for (int m = 0; m < 4; ++m) a[m]  = As[kk*65 + ty*4 + m];
            #pragma unroll
            for (int n = 0; n < 4; ++n) bb[n] = Bs[kk*64 + tx*4 + n];
            #pragma unroll
            for (int m = 0; m < 4; ++m)
                #pragma unroll
                for (int n = 0; n < 4; ++n)
                    acc[m][n] += a[m] * bb[n];
        }
        __syncthreads();
    }
    #pragma unroll
    for (int m = 0; m < 4; ++m)
        #pragma unroll
        for (int n = 0; n < 4; ++n) {
            const int col = col0 + tx*4 + n;
            float v = acc[m][n];
            if (bias) v += bias[col];
            C[(size_t)(row0 + ty*4 + m) * Nn + col] = v;
        }
}

// ---------------- Kernel C: fused neighbor attention per (b,i) ----------------
__global__ __launch_bounds__(256) void attn_kernel(const float* __restrict__ qkv,
                                                   const float* __restrict__ coors,
                                                   const int* __restrict__ nbhd,
                                                   const float* __restrict__ w_c1,
                                                   const float* __restrict__ b_c1,
                                                   const float* __restrict__ w_c2,
                                                   const float* __restrict__ b_c2,
                                                   const float* __restrict__ ln_b,
                                                   float* __restrict__ out_pre,
                                                   float* __restrict__ coors_out) {
    __shared__ float vg[KNN_ * VROW_];      // 32.5 KB rotated v, padded rows
    __shared__ float qkl[KNN_][HEADS_];
    __shared__ float attnl[KNN_][HEADS_];
    __shared__ float coorw[KNN_];
    __shared__ float distl[KNN_];           // holds dist*100
    __shared__ float ul[KNN_][3];
    __shared__ int   njl[KNN_];

    const int bi = blockIdx.x;
    const int b = bi >> 12;
    const int i = bi & (N_ - 1);
    const int t = threadIdx.x;
    const int w = t >> 6;                   // wave id
    const int l = t & 63;                   // lane
    const float* cb = coors + (size_t)b * N_ * 3;

    if (t < KNN_) {
        const int nj = nbhd[(size_t)bi * KNN_ + t];
        njl[t] = nj;
        const float dx = cb[i*3+0] - cb[nj*3+0];
        const float dy = cb[i*3+1] - cb[nj*3+1];
        const float dz = cb[i*3+2] - cb[nj*3+2];
        const float dist = sqrtf(dx*dx + dy*dy + dz*dz);
        distl[t] = dist * 100.0f;
        const float den = fmaxf(dist, 1e-8f);
        ul[t][0] = dx / den; ul[t][1] = dy / den; ul[t][2] = dz / den;
    }

    const float4 q4 = *(const float4*)(qkv + (size_t)bi * QKVW_ + 4*l);
    const int li = l & 15;
    const bool rot = li < 8;
    const float invf0 = exp2f(-(float)(2*li    ) * 0.8304820237218407f);  // log2(1e4)/16
    const float invf1 = exp2f(-(float)(2*li + 1) * 0.8304820237218407f);
    __syncthreads();

    #pragma unroll 2
    for (int jj = 0; jj < 8; ++jj) {
        const int j = w*8 + jj;
        const int nj = njl[j];
        const float* base = qkv + (size_t)(b * N_ + nj) * QKVW_;
        float4 k4 = *(const float4*)(base + INNER_   + 4*l);
        float4 v4 = *(const float4*)(base + 2*INNER_ + 4*l);
        if (rot) {
            const float d100 = distl[j];
            float s0, c0, s1, c1;
            sincosf(d100 * invf0, &s0, &c0);
            sincosf(d100 * invf1, &s1, &c1);
            float x;
            x = k4.x; k4.x = x*c0 - k4.y*s0; k4.y = k4.y*c0 + x*s0;
            x = k4.z; k4.z = x*c1 - k4.w*s1; k4.w = k4.w*c1 + x*s1;
            x = v4.x; v4.x = x*c0 - v4.y*s0; v4.y = v4.y*c0 + x*s0;
            x = v4.z; v4.z = x*c1 - v4.w*s1; v4.w = v4.w*c1 + x*s1;
        }
        *(float4*)&vg[j * VROW_ + 4*l] = v4;
        float p = q4.x*k4.x + q4.y*k4.y + q4.z*k4.z + q4.w*k4.w;
        p += __shfl_xor(p, 1);
        p += __shfl_xor(p, 2);
        p += __shfl_xor(p, 4);
        p += __shfl_xor(p, 8);
        if (li == 0) qkl[j][l >> 4] = p * 0.125f;   // * dh^-0.5
    }
    __syncthreads();

    {
        const int d = l;
        const float x = (d < KNN_) ? qkl[d][w] : -INFINITY;
        float mx = x;
        #pragma unroll
        for (int off = 32; off; off >>= 1) mx = fmaxf(mx, __shfl_xor(mx, off));
        const float e = expf(x - mx);
        float s = e;
        #pragma unroll
        for (int off = 32; off; off >>= 1) s += __shfl_xor(s, off);
        if (d < KNN_) attnl[d][w] = e / s;
    }

    if (t < KNN_) {
        const float q0 = qkl[t][0], q1 = qkl[t][1], q2 = qkl[t][2], q3 = qkl[t][3];
        float cw = b_c2[0];
        #pragma unroll
        for (int mh = 0; mh < 16; ++mh) {
            const float hv = q0*w_c1[0*16+mh] + q1*w_c1[1*16+mh]
                           + q2*w_c1[2*16+mh] + q3*w_c1[3*16+mh] + b_c1[mh];
            const float g = 0.5f * hv * (1.0f + erff(hv * 0.70710678118654752440f));
            cw += g * w_c2[mh];
        }
        coorw[t] = cw;
    }
    __syncthreads();

    float o = 0.0f;
    #pragma unroll
    for (int j = 0; j < KNN_; ++j) o += attnl[j][w] * vg[j * VROW_ + t];
    out_pre[(size_t)bi * INNER_ + t] = o;

    if (t < 3) {
        float acc = 0.0f;
        #pragma unroll
        for (int j = 0; j < KNN_; ++j) acc += coorw[j] * ul[j][t];
        coors_out[(size_t)bi * 3 + t] = acc * ln_b[0];
    }
}

extern "C" void kernel_launch(void* const* d_in, const int* in_sizes, int n_in,
                              void* d_out, int out_size, void* d_ws, size_t ws_size,
                              hipStream_t stream) {
    (void)in_sizes; (void)n_in; (void)out_size; (void)ws_size;
    const float* feats = (const float*)d_in[0];
    const float* coors = (const float*)d_in[1];
    const float* w_qkv = (const float*)d_in[2];
    const float* w_out = (const float*)d_in[3];
    const float* b_out = (const float*)d_in[4];
    const float* w_c1  = (const float*)d_in[5];
    const float* b_c1  = (const float*)d_in[6];
    const float* w_c2  = (const float*)d_in[7];
    const float* b_c2  = (const float*)d_in[8];
    const float* ln_b  = (const float*)d_in[10];   // ln_g (d_in[9]) is dead

    const int M = B_ * N_;                          // 8192
    float* ws      = (float*)d_ws;
    float* qkv     = ws;                            // 8192*768 floats
    int*   nbhd    = (int*)(ws + (size_t)M * QKVW_);// 8192*32 ints
    float* out_pre = ws + (size_t)M * QKVW_ + (size_t)M * KNN_; // 8192*256 floats

    float* out_main  = (float*)d_out;               // 8192*256
    float* out_coors = out_main + (size_t)M * DIM_; // 8192*3

    gemm_kernel<<<dim3(QKVW_/64, M/64), 256, 0, stream>>>(feats, w_qkv, nullptr, qkv,
                                                          M, DIM_, QKVW_);
    knn_kernel<<<M, 256, 0, stream>>>(coors, nbhd);
    attn_kernel<<<M, 256, 0, stream>>>(qkv, coors, nbhd, w_c1, b_c1, w_c2, b_c2, ln_b,
                                       out_pre, out_coors);
    gemm_kernel<<<dim3(DIM_/64, M/64), 256, 0, stream>>>(out_pre, w_out, b_out, out_main,
                                                         M, DIM_, DIM_);
}

// Round 6
// 203.482 us; speedup vs baseline: 2.7233x; 1.0095x over previous
//
#include <hip/hip_runtime.h>
#include <math.h>

#define B_ 2
#define N_ 4096
#define DIM_ 256
#define HEADS_ 4
#define DH_ 64
#define KNN_ 32
#define INNER_ 256       // HEADS*DH
#define QKVW_ 768        // 3*INNER
#define HB_ 512          // histogram bins
#define CAND_ 512        // boundary-bin candidate cap
#define VROW_ 260        // padded vg row (floats)

static __device__ __forceinline__ unsigned long long ullmin2(unsigned long long a, unsigned long long b) {
    return a < b ? a : b;
}

// sin/cos of (2*pi*rev) via HW trans ops; rev >= 0.
static __device__ __forceinline__ void sincos_rev(float rev, float* s, float* c) {
    const float fr = rev - floorf(rev);      // v_fract
    float ss, cc;
    asm("v_sin_f32 %0, %1" : "=v"(ss) : "v"(fr));
    asm("v_cos_f32 %0, %1" : "=v"(cc) : "v"(fr));
    *s = ss; *c = cc;
}

// ---------------- Kernel A: exact KNN via histogram select ----------------
__global__ __launch_bounds__(256) void knn_kernel(const float* __restrict__ coors,
                                                  int* __restrict__ nbhd) {
    __shared__ float dists[N_];                 // 16 KB
    __shared__ int   hist[HB_];                 // 2 KB
    __shared__ unsigned long long cand[CAND_];  // 4 KB
    __shared__ float tminf[256];
    __shared__ float Msh;
    __shared__ int   bsh, clsh, candcnt, outcnt;

    const int bi = blockIdx.x;
    const int b = bi >> 12;            // N_ = 4096
    const int i = bi & (N_ - 1);
    const int t = threadIdx.x;
    const float* cb = coors + (size_t)b * N_ * 3;
    const float xi = cb[i*3+0], yi = cb[i*3+1], zi = cb[i*3+2];

    float mymin = INFINITY;
    #pragma unroll
    for (int l = 0; l < N_/256; ++l) {
        const int j = t + l*256;
        const float dx = xi - cb[j*3+0];
        const float dy = yi - cb[j*3+1];
        const float dz = zi - cb[j*3+2];
        const float d = sqrtf(dx*dx + dy*dy + dz*dz);
        dists[j] = d;
        mymin = fminf(mymin, d);
    }
    tminf[t] = mymin;
    hist[t] = 0; hist[t + 256] = 0;
    if (t == 0) { candcnt = 0; outcnt = 0; }
    __syncthreads();

    if (t < 64) {
        float m4 = fmaxf(fmaxf(tminf[t], tminf[t+64]), fmaxf(tminf[t+128], tminf[t+192]));
        #pragma unroll
        for (int off = 32; off; off >>= 1) m4 = fmaxf(m4, __shfl_xor(m4, off));
        if (t == 0) Msh = fmaxf(m4, 1e-20f);
    }
    __syncthreads();

    const float Mv = Msh;
    const float scale = (float)(HB_ - 1) / Mv;

    // histogram of RELEVANT distances only (d <= M; >=256 dists are <= M so
    // the 32nd smallest is <= M — skipping d > M cannot change selection)
    #pragma unroll
    for (int l = 0; l < N_/256; ++l) {
        const int j = t + l*256;
        const float d = dists[j];
        if (d <= Mv) {
            const int bin = (int)fminf(d * scale, (float)(HB_ - 1));
            atomicAdd(&hist[bin], 1);
        }
    }
    __syncthreads();

    if (t < 64) {
        int s = 0;
        #pragma unroll
        for (int k = 0; k < HB_/64; ++k) s += hist[t*(HB_/64) + k];
        int inc = s;
        #pragma unroll
        for (int off = 1; off < 64; off <<= 1) {
            const int v = __shfl_up(inc, off);
            if (t >= off) inc += v;
        }
        const int excl = inc - s;
        if (excl < KNN_ && inc >= KNN_) {
            int cum = excl;
            #pragma unroll
            for (int k = 0; k < HB_/64; ++k) {
                const int c = hist[t*(HB_/64) + k];
                if (cum + c >= KNN_) { bsh = t*(HB_/64) + k; clsh = cum; break; }
                cum += c;
            }
        }
    }
    __syncthreads();

    const int bbin = bsh, c_less = clsh;

    #pragma unroll
    for (int l = 0; l < N_/256; ++l) {
        const int j = t + l*256;
        const float d = dists[j];
        if (d <= Mv) {
            const int bin = (int)fminf(d * scale, (float)(HB_ - 1));
            if (bin < bbin) {
                const int slot = atomicAdd(&outcnt, 1);
                nbhd[(size_t)bi * KNN_ + slot] = j;
            } else if (bin == bbin) {
                const int c = atomicAdd(&candcnt, 1);
                if (c < CAND_) {
                    cand[c] = ((unsigned long long)__float_as_uint(d) << 32) | (unsigned)j;
                }
            }
        }
    }
    __syncthreads();

    const int m = KNN_ - c_less;
    const int e = candcnt;
    if (e <= CAND_) {
        if (t < 64) {
            for (int r = 0; r < m; ++r) {
                unsigned long long v = ~0ULL;
                for (int idx = t; idx < e; idx += 64) v = ullmin2(v, cand[idx]);
                #pragma unroll
                for (int off = 32; off; off >>= 1) v = ullmin2(v, __shfl_xor(v, off));
                if (t == 0) nbhd[(size_t)bi * KNN_ + c_less + r] = (int)(v & 0xffffffffu);
                for (int idx = t; idx < e; idx += 64)
                    if (cand[idx] == v) cand[idx] = ~0ULL;
            }
        }
    } else if (t == 0) {
        for (int r = 0; r < m; ++r) {
            unsigned long long best = ~0ULL;
            for (int j = 0; j < N_; ++j) {
                const float d = dists[j];
                if (d <= Mv) {
                    const int bin = (int)fminf(d * scale, (float)(HB_ - 1));
                    if (bin == bbin) {
                        const unsigned long long key =
                            ((unsigned long long)__float_as_uint(d) << 32) | (unsigned)j;
                        best = ullmin2(best, key);
                    }
                }
            }
            const int wj = (int)(best & 0xffffffffu);
            nbhd[(size_t)bi * KNN_ + c_less + r] = wj;
            dists[wj] = INFINITY;
        }
    }
}

// ---------------- generic f32 tiled GEMM: C = A(MxK) @ Bm(KxN) (+bias) ----------------
__global__ __launch_bounds__(256) void gemm_kernel(const float* __restrict__ A,
                                                   const float* __restrict__ Bm,
                                                   const float* __restrict__ bias,
                                                   float* __restrict__ C,
                                                   int M, int K, int Nn) {
    __shared__ float As[32*65];   // [k][m], padded
    __shared__ float Bs[32*64];   // [k][n]
    const int tx = threadIdx.x & 15, ty = threadIdx.x >> 4;
    const int row0 = blockIdx.y * 64, col0 = blockIdx.x * 64;
    float acc[4][4] = {};
    for (int k0 = 0; k0 < K; k0 += 32) {
        #pragma unroll
        for (int l = 0; l < 8; ++l) {
            const int idx = l*256 + threadIdx.x;
            const int r  = idx >> 5, c  = idx & 31;
            As[c*65 + r] = A[(size_t)(row0 + r) * K + k0 + c];
            const int r2 = idx >> 6, c2 = idx & 63;
            Bs[r2*64 + c2] = Bm[(size_t)(k0 + r2) * Nn + col0 + c2];
        }
        __syncthreads();
        #pragma unroll
        for (int kk = 0; kk < 32; ++kk) {
            float a[4], bb[4];
            #pragma unroll
            for (int m = 0; m < 4; ++m) a[m]  = As[kk*65 + ty*4 + m];
            #pragma unroll
            for (int n = 0; n < 4; ++n) bb[n] = Bs[kk*64 + tx*4 + n];
            #pragma unroll
            for (int m = 0; m < 4; ++m)
                #pragma unroll
                for (int n = 0; n < 4; ++n)
                    acc[m][n] += a[m] * bb[n];
        }
        __syncthreads();
    }
    #pragma unroll
    for (int m = 0; m < 4; ++m)
        #pragma unroll
        for (int n = 0; n < 4; ++n) {
            const int col = col0 + tx*4 + n;
            float v = acc[m][n];
            if (bias) v += bias[col];
            C[(size_t)(row0 + ty*4 + m) * Nn + col] = v;
        }
}

// ---------------- Kernel C: fused neighbor attention per (b,i) ----------------
__global__ __launch_bounds__(256) void attn_kernel(const float* __restrict__ qkv,
                                                   const float* __restrict__ coors,
                                                   const int* __restrict__ nbhd,
                                                   const float* __restrict__ w_c1,
                                                   const float* __restrict__ b_c1,
                                                   const float* __restrict__ w_c2,
                                                   const float* __restrict__ b_c2,
                                                   const float* __restrict__ ln_b,
                                                   float* __restrict__ out_pre,
                                                   float* __restrict__ coors_out) {
    __shared__ float vg[KNN_ * VROW_];      // 32.5 KB rotated v, padded rows
    __shared__ float qkl[KNN_][HEADS_];
    __shared__ float attnl[KNN_][HEADS_];
    __shared__ float coorw[KNN_];
    __shared__ float distl[KNN_];           // holds dist*100
    __shared__ float ul[KNN_][3];
    __shared__ int   njl[KNN_];

    const int bi = blockIdx.x;
    const int b = bi >> 12;
    const int i = bi & (N_ - 1);
    const int t = threadIdx.x;
    const int w = t >> 6;                   // wave id
    const int l = t & 63;                   // lane
    const float* cb = coors + (size_t)b * N_ * 3;

    if (t < KNN_) {
        const int nj = nbhd[(size_t)bi * KNN_ + t];
        njl[t] = nj;
        const float dx = cb[i*3+0] - cb[nj*3+0];
        const float dy = cb[i*3+1] - cb[nj*3+1];
        const float dz = cb[i*3+2] - cb[nj*3+2];
        const float dist = sqrtf(dx*dx + dy*dy + dz*dz);
        distl[t] = dist * 100.0f;
        const float den = fmaxf(dist, 1e-8f);
        ul[t][0] = dx / den; ul[t][1] = dy / den; ul[t][2] = dz / den;
    }

    const float4 q4 = *(const float4*)(qkv + (size_t)bi * QKVW_ + 4*l);
    // rotary: dims-in-head dd = 4*(l&15); rotate iff dd < 32. Angles in
    // REVOLUTIONS: rev = d100 * invf / (2*pi)  ->  HW v_sin/v_cos.
    const int li = l & 15;
    const bool rot = li < 8;
    const float invf0r = exp2f(-(float)(2*li    ) * 0.8304820237218407f) * 0.15915494309189535f;
    const float invf1r = exp2f(-(float)(2*li + 1) * 0.8304820237218407f) * 0.15915494309189535f;
    __syncthreads();

    #pragma unroll 4
    for (int jj = 0; jj < 8; ++jj) {
        const int j = w*8 + jj;
        const int nj = njl[j];
        const float* base = qkv + (size_t)(b * N_ + nj) * QKVW_;
        float4 k4 = *(const float4*)(base + INNER_   + 4*l);
        float4 v4 = *(const float4*)(base + 2*INNER_ + 4*l);
        if (rot) {
            const float d100 = distl[j];
            float s0, c0, s1, c1;
            sincos_rev(d100 * invf0r, &s0, &c0);
            sincos_rev(d100 * invf1r, &s1, &c1);
            float x;
            x = k4.x; k4.x = x*c0 - k4.y*s0; k4.y = k4.y*c0 + x*s0;
            x = k4.z; k4.z = x*c1 - k4.w*s1; k4.w = k4.w*c1 + x*s1;
            x = v4.x; v4.x = x*c0 - v4.y*s0; v4.y = v4.y*c0 + x*s0;
            x = v4.z; v4.z = x*c1 - v4.w*s1; v4.w = v4.w*c1 + x*s1;
        }
        *(float4*)&vg[j * VROW_ + 4*l] = v4;
        float p = q4.x*k4.x + q4.y*k4.y + q4.z*k4.z + q4.w*k4.w;
        p += __shfl_xor(p, 1);
        p += __shfl_xor(p, 2);
        p += __shfl_xor(p, 4);
        p += __shfl_xor(p, 8);
        if (li == 0) qkl[j][l >> 4] = p * 0.125f;   // * dh^-0.5
    }
    __syncthreads();

    {
        const int d = l;
        const float x = (d < KNN_) ? qkl[d][w] : -INFINITY;
        float mx = x;
        #pragma unroll
        for (int off = 32; off; off >>= 1) mx = fmaxf(mx, __shfl_xor(mx, off));
        const float e = expf(x - mx);
        float s = e;
        #pragma unroll
        for (int off = 32; off; off >>= 1) s += __shfl_xor(s, off);
        if (d < KNN_) attnl[d][w] = e / s;
    }

    if (t < KNN_) {
        const float q0 = qkl[t][0], q1 = qkl[t][1], q2 = qkl[t][2], q3 = qkl[t][3];
        float cw = b_c2[0];
        #pragma unroll
        for (int mh = 0; mh < 16; ++mh) {
            const float hv = q0*w_c1[0*16+mh] + q1*w_c1[1*16+mh]
                           + q2*w_c1[2*16+mh] + q3*w_c1[3*16+mh] + b_c1[mh];
            const float g = 0.5f * hv * (1.0f + erff(hv * 0.70710678118654752440f));
            cw += g * w_c2[mh];
        }
        coorw[t] = cw;
    }
    __syncthreads();

    float o = 0.0f;
    #pragma unroll
    for (int j = 0; j < KNN_; ++j) o += attnl[j][w] * vg[j * VROW_ + t];
    out_pre[(size_t)bi * INNER_ + t] = o;

    if (t < 3) {
        float acc = 0.0f;
        #pragma unroll
        for (int j = 0; j < KNN_; ++j) acc += coorw[j] * ul[j][t];
        coors_out[(size_t)bi * 3 + t] = acc * ln_b[0];
    }
}

extern "C" void kernel_launch(void* const* d_in, const int* in_sizes, int n_in,
                              void* d_out, int out_size, void* d_ws, size_t ws_size,
                              hipStream_t stream) {
    (void)in_sizes; (void)n_in; (void)out_size; (void)ws_size;
    const float* feats = (const float*)d_in[0];
    const float* coors = (const float*)d_in[1];
    const float* w_qkv = (const float*)d_in[2];
    const float* w_out = (const float*)d_in[3];
    const float* b_out = (const float*)d_in[4];
    const float* w_c1  = (const float*)d_in[5];
    const float* b_c1  = (const float*)d_in[6];
    const float* w_c2  = (const float*)d_in[7];
    const float* b_c2  = (const float*)d_in[8];
    const float* ln_b  = (const float*)d_in[10];   // ln_g (d_in[9]) is dead

    const int M = B_ * N_;                          // 8192
    float* ws      = (float*)d_ws;
    float* qkv     = ws;                            // 8192*768 floats
    int*   nbhd    = (int*)(ws + (size_t)M * QKVW_);// 8192*32 ints
    float* out_pre = ws + (size_t)M * QKVW_ + (size_t)M * KNN_; // 8192*256 floats

    float* out_main  = (float*)d_out;               // 8192*256
    float* out_coors = out_main + (size_t)M * DIM_; // 8192*3

    gemm_kernel<<<dim3(QKVW_/64, M/64), 256, 0, stream>>>(feats, w_qkv, nullptr, qkv,
                                                          M, DIM_, QKVW_);
    knn_kernel<<<M, 256, 0, stream>>>(coors, nbhd);
    attn_kernel<<<M, 256, 0, stream>>>(qkv, coors, nbhd, w_c1, b_c1, w_c2, b_c2, ln_b,
                                       out_pre, out_coors);
    gemm_kernel<<<dim3(DIM_/64, M/64), 256, 0, stream>>>(out_pre, w_out, b_out, out_main,
                                                         M, DIM_, DIM_);
}

// Round 7
// 181.987 us; speedup vs baseline: 3.0450x; 1.1181x over previous
//
#include <hip/hip_runtime.h>
#include <hip/hip_fp16.h>
#include <math.h>

#define B_ 2
#define N_ 4096
#define DIM_ 256
#define HEADS_ 4
#define DH_ 64
#define KNN_ 32
#define INNER_ 256       // HEADS*DH
#define QKVW_ 768        // 3*INNER
#define HB_ 512          // histogram bins
#define CAND_ 512        // boundary-bin candidate cap

static __device__ __forceinline__ unsigned long long ullmin2(unsigned long long a, unsigned long long b) {
    return a < b ? a : b;
}

// sin/cos of (2*pi*rev) via HW trans ops; rev >= 0.
static __device__ __forceinline__ void sincos_rev(float rev, float* s, float* c) {
    const float fr = rev - floorf(rev);      // v_fract
    float ss, cc;
    asm("v_sin_f32 %0, %1" : "=v"(ss) : "v"(fr));
    asm("v_cos_f32 %0, %1" : "=v"(cc) : "v"(fr));
    *s = ss; *c = cc;
}

// ---------------- Kernel A: exact KNN via histogram select ----------------
__global__ __launch_bounds__(256) void knn_kernel(const float* __restrict__ coors,
                                                  int* __restrict__ nbhd) {
    __shared__ float dists[N_];                 // 16 KB
    __shared__ int   hist[HB_];                 // 2 KB
    __shared__ unsigned long long cand[CAND_];  // 4 KB
    __shared__ float tminf[256];
    __shared__ float Msh;
    __shared__ int   bsh, clsh, candcnt, outcnt;

    const int bi = blockIdx.x;
    const int b = bi >> 12;            // N_ = 4096
    const int i = bi & (N_ - 1);
    const int t = threadIdx.x;
    const float* cb = coors + (size_t)b * N_ * 3;
    const float xi = cb[i*3+0], yi = cb[i*3+1], zi = cb[i*3+2];

    float mymin = INFINITY;
    #pragma unroll
    for (int l = 0; l < N_/256; ++l) {
        const int j = t + l*256;
        const float dx = xi - cb[j*3+0];
        const float dy = yi - cb[j*3+1];
        const float dz = zi - cb[j*3+2];
        const float d = sqrtf(dx*dx + dy*dy + dz*dz);
        dists[j] = d;
        mymin = fminf(mymin, d);
    }
    tminf[t] = mymin;
    hist[t] = 0; hist[t + 256] = 0;
    if (t == 0) { candcnt = 0; outcnt = 0; }
    __syncthreads();

    if (t < 64) {
        float m4 = fmaxf(fmaxf(tminf[t], tminf[t+64]), fmaxf(tminf[t+128], tminf[t+192]));
        #pragma unroll
        for (int off = 32; off; off >>= 1) m4 = fmaxf(m4, __shfl_xor(m4, off));
        if (t == 0) Msh = fmaxf(m4, 1e-20f);
    }
    __syncthreads();

    const float Mv = Msh;
    const float scale = (float)(HB_ - 1) / Mv;

    // histogram of RELEVANT distances only (d <= M; >=256 dists are <= M so
    // the 32nd smallest is <= M — skipping d > M cannot change selection)
    #pragma unroll
    for (int l = 0; l < N_/256; ++l) {
        const int j = t + l*256;
        const float d = dists[j];
        if (d <= Mv) {
            const int bin = (int)fminf(d * scale, (float)(HB_ - 1));
            atomicAdd(&hist[bin], 1);
        }
    }
    __syncthreads();

    if (t < 64) {
        int s = 0;
        #pragma unroll
        for (int k = 0; k < HB_/64; ++k) s += hist[t*(HB_/64) + k];
        int inc = s;
        #pragma unroll
        for (int off = 1; off < 64; off <<= 1) {
            const int v = __shfl_up(inc, off);
            if (t >= off) inc += v;
        }
        const int excl = inc - s;
        if (excl < KNN_ && inc >= KNN_) {
            int cum = excl;
            #pragma unroll
            for (int k = 0; k < HB_/64; ++k) {
                const int c = hist[t*(HB_/64) + k];
                if (cum + c >= KNN_) { bsh = t*(HB_/64) + k; clsh = cum; break; }
                cum += c;
            }
        }
    }
    __syncthreads();

    const int bbin = bsh, c_less = clsh;

    #pragma unroll
    for (int l = 0; l < N_/256; ++l) {
        const int j = t + l*256;
        const float d = dists[j];
        if (d <= Mv) {
            const int bin = (int)fminf(d * scale, (float)(HB_ - 1));
            if (bin < bbin) {
                const int slot = atomicAdd(&outcnt, 1);
                nbhd[(size_t)bi * KNN_ + slot] = j;
            } else if (bin == bbin) {
                const int c = atomicAdd(&candcnt, 1);
                if (c < CAND_) {
                    cand[c] = ((unsigned long long)__float_as_uint(d) << 32) | (unsigned)j;
                }
            }
        }
    }
    __syncthreads();

    const int m = KNN_ - c_less;
    const int e = candcnt;
    if (e <= CAND_) {
        if (t < 64) {
            for (int r = 0; r < m; ++r) {
                unsigned long long v = ~0ULL;
                for (int idx = t; idx < e; idx += 64) v = ullmin2(v, cand[idx]);
                #pragma unroll
                for (int off = 32; off; off >>= 1) v = ullmin2(v, __shfl_xor(v, off));
                if (t == 0) nbhd[(size_t)bi * KNN_ + c_less + r] = (int)(v & 0xffffffffu);
                for (int idx = t; idx < e; idx += 64)
                    if (cand[idx] == v) cand[idx] = ~0ULL;
            }
        }
    } else if (t == 0) {
        for (int r = 0; r < m; ++r) {
            unsigned long long best = ~0ULL;
            for (int j = 0; j < N_; ++j) {
                const float d = dists[j];
                if (d <= Mv) {
                    const int bin = (int)fminf(d * scale, (float)(HB_ - 1));
                    if (bin == bbin) {
                        const unsigned long long key =
                            ((unsigned long long)__float_as_uint(d) << 32) | (unsigned)j;
                        best = ullmin2(best, key);
                    }
                }
            }
            const int wj = (int)(best & 0xffffffffu);
            nbhd[(size_t)bi * KNN_ + c_less + r] = wj;
            dists[wj] = INFINITY;
        }
    }
}

// ---------------- generic f32 tiled GEMM: C = A(MxK) @ Bm(KxN) (+bias) ----------------
__global__ __launch_bounds__(256) void gemm_kernel(const float* __restrict__ A,
                                                   const float* __restrict__ Bm,
                                                   const float* __restrict__ bias,
                                                   float* __restrict__ C,
                                                   int M, int K, int Nn) {
    __shared__ float As[32*65];   // [k][m], padded
    __shared__ float Bs[32*64];   // [k][n]
    const int tx = threadIdx.x & 15, ty = threadIdx.x >> 4;
    const int row0 = blockIdx.y * 64, col0 = blockIdx.x * 64;
    float acc[4][4] = {};
    for (int k0 = 0; k0 < K; k0 += 32) {
        #pragma unroll
        for (int l = 0; l < 8; ++l) {
            const int idx = l*256 + threadIdx.x;
            const int r  = idx >> 5, c  = idx & 31;
            As[c*65 + r] = A[(size_t)(row0 + r) * K + k0 + c];
            const int r2 = idx >> 6, c2 = idx & 63;
            Bs[r2*64 + c2] = Bm[(size_t)(k0 + r2) * Nn + col0 + c2];
        }
        __syncthreads();
        #pragma unroll
        for (int kk = 0; kk < 32; ++kk) {
            float a[4], bb[4];
            #pragma unroll
            for (int m = 0; m < 4; ++m) a[m]  = As[kk*65 + ty*4 + m];
            #pragma unroll
            for (int n = 0; n < 4; ++n) bb[n] = Bs[kk*64 + tx*4 + n];
            #pragma unroll
            for (int m = 0; m < 4; ++m)
                #pragma unroll
                for (int n = 0; n < 4; ++n)
                    acc[m][n] += a[m] * bb[n];
        }
        __syncthreads();
    }
    #pragma unroll
    for (int m = 0; m < 4; ++m)
        #pragma unroll
        for (int n = 0; n < 4; ++n) {
            const int col = col0 + tx*4 + n;
            float v = acc[m][n];
            if (bias) v += bias[col];
            C[(size_t)(row0 + ty*4 + m) * Nn + col] = v;
        }
}

// ---------------- Kernel C: fused neighbor attention per (b,i) ----------------
// 4 waves; wave w owns neighbors w*8..w*8+7; lane l owns dims [4l..4l+3].
// Rotated V staged in LDS as f16 (halves LDS -> 8 blocks/CU -> 100% occupancy).
__global__ __launch_bounds__(256) void attn_kernel(const float* __restrict__ qkv,
                                                   const float* __restrict__ coors,
                                                   const int* __restrict__ nbhd,
                                                   const float* __restrict__ w_c1,
                                                   const float* __restrict__ b_c1,
                                                   const float* __restrict__ w_c2,
                                                   const float* __restrict__ b_c2,
                                                   const float* __restrict__ ln_b,
                                                   float* __restrict__ out_pre,
                                                   float* __restrict__ coors_out) {
    __shared__ __half vgh[KNN_ * INNER_];   // 16 KB rotated v (f16)
    __shared__ float qkl[KNN_][HEADS_];
    __shared__ float attnl[KNN_][HEADS_];
    __shared__ float coorw[KNN_];
    __shared__ float distl[KNN_];           // holds dist*100
    __shared__ float ul[KNN_][3];
    __shared__ int   njl[KNN_];

    const int bi = blockIdx.x;
    const int b = bi >> 12;
    const int i = bi & (N_ - 1);
    const int t = threadIdx.x;
    const int w = t >> 6;                   // wave id
    const int l = t & 63;                   // lane
    const float* cb = coors + (size_t)b * N_ * 3;

    if (t < KNN_) {
        const int nj = nbhd[(size_t)bi * KNN_ + t];
        njl[t] = nj;
        const float dx = cb[i*3+0] - cb[nj*3+0];
        const float dy = cb[i*3+1] - cb[nj*3+1];
        const float dz = cb[i*3+2] - cb[nj*3+2];
        const float dist = sqrtf(dx*dx + dy*dy + dz*dz);
        distl[t] = dist * 100.0f;
        const float den = fmaxf(dist, 1e-8f);
        ul[t][0] = dx / den; ul[t][1] = dy / den; ul[t][2] = dz / den;
    }

    const float4 q4 = *(const float4*)(qkv + (size_t)bi * QKVW_ + 4*l);
    // rotary: dims-in-head dd = 4*(l&15); rotate iff dd < 32. Angles in
    // REVOLUTIONS: rev = d100 * invf / (2*pi)  ->  HW v_sin/v_cos.
    const int li = l & 15;
    const bool rot = li < 8;
    const float invf0r = exp2f(-(float)(2*li    ) * 0.8304820237218407f) * 0.15915494309189535f;
    const float invf1r = exp2f(-(float)(2*li + 1) * 0.8304820237218407f) * 0.15915494309189535f;
    __syncthreads();

    #pragma unroll 4
    for (int jj = 0; jj < 8; ++jj) {
        const int j = w*8 + jj;
        const int nj = njl[j];
        const float* base = qkv + (size_t)(b * N_ + nj) * QKVW_;
        float4 k4 = *(const float4*)(base + INNER_   + 4*l);
        float4 v4 = *(const float4*)(base + 2*INNER_ + 4*l);
        if (rot) {
            const float d100 = distl[j];
            float s0, c0, s1, c1;
            sincos_rev(d100 * invf0r, &s0, &c0);
            sincos_rev(d100 * invf1r, &s1, &c1);
            float x;
            x = k4.x; k4.x = x*c0 - k4.y*s0; k4.y = k4.y*c0 + x*s0;
            x = k4.z; k4.z = x*c1 - k4.w*s1; k4.w = k4.w*c1 + x*s1;
            x = v4.x; v4.x = x*c0 - v4.y*s0; v4.y = v4.y*c0 + x*s0;
            x = v4.z; v4.z = x*c1 - v4.w*s1; v4.w = v4.w*c1 + x*s1;
        }
        {   // pack v4 -> 4 halfs, single 8 B LDS write
            union { __half2 h2[2]; uint2 u; } pk;
            pk.h2[0] = __floats2half2_rn(v4.x, v4.y);
            pk.h2[1] = __floats2half2_rn(v4.z, v4.w);
            *reinterpret_cast<uint2*>(&vgh[j * INNER_ + 4*l]) = pk.u;
        }
        float p = q4.x*k4.x + q4.y*k4.y + q4.z*k4.z + q4.w*k4.w;
        p += __shfl_xor(p, 1);
        p += __shfl_xor(p, 2);
        p += __shfl_xor(p, 4);
        p += __shfl_xor(p, 8);
        if (li == 0) qkl[j][l >> 4] = p * 0.125f;   // * dh^-0.5
    }
    __syncthreads();

    {
        const int d = l;
        const float x = (d < KNN_) ? qkl[d][w] : -INFINITY;
        float mx = x;
        #pragma unroll
        for (int off = 32; off; off >>= 1) mx = fmaxf(mx, __shfl_xor(mx, off));
        const float e = expf(x - mx);
        float s = e;
        #pragma unroll
        for (int off = 32; off; off >>= 1) s += __shfl_xor(s, off);
        if (d < KNN_) attnl[d][w] = e / s;
    }

    if (t < KNN_) {
        const float q0 = qkl[t][0], q1 = qkl[t][1], q2 = qkl[t][2], q3 = qkl[t][3];
        float cw = b_c2[0];
        #pragma unroll
        for (int mh = 0; mh < 16; ++mh) {
            const float hv = q0*w_c1[0*16+mh] + q1*w_c1[1*16+mh]
                           + q2*w_c1[2*16+mh] + q3*w_c1[3*16+mh] + b_c1[mh];
            const float g = 0.5f * hv * (1.0f + erff(hv * 0.70710678118654752440f));
            cw += g * w_c2[mh];
        }
        coorw[t] = cw;
    }
    __syncthreads();

    // out[t] = sum_j attn[j][w] * v[j][t]   (dim t's head == w)
    float o = 0.0f;
    #pragma unroll
    for (int j = 0; j < KNN_; ++j)
        o += attnl[j][w] * __half2float(vgh[j * INNER_ + t]);
    out_pre[(size_t)bi * INNER_ + t] = o;

    if (t < 3) {
        float acc = 0.0f;
        #pragma unroll
        for (int j = 0; j < KNN_; ++j) acc += coorw[j] * ul[j][t];
        coors_out[(size_t)bi * 3 + t] = acc * ln_b[0];
    }
}

extern "C" void kernel_launch(void* const* d_in, const int* in_sizes, int n_in,
                              void* d_out, int out_size, void* d_ws, size_t ws_size,
                              hipStream_t stream) {
    (void)in_sizes; (void)n_in; (void)out_size; (void)ws_size;
    const float* feats = (const float*)d_in[0];
    const float* coors = (const float*)d_in[1];
    const float* w_qkv = (const float*)d_in[2];
    const float* w_out = (const float*)d_in[3];
    const float* b_out = (const float*)d_in[4];
    const float* w_c1  = (const float*)d_in[5];
    const float* b_c1  = (const float*)d_in[6];
    const float* w_c2  = (const float*)d_in[7];
    const float* b_c2  = (const float*)d_in[8];
    const float* ln_b  = (const float*)d_in[10];   // ln_g (d_in[9]) is dead

    const int M = B_ * N_;                          // 8192
    float* ws      = (float*)d_ws;
    float* qkv     = ws;                            // 8192*768 floats
    int*   nbhd    = (int*)(ws + (size_t)M * QKVW_);// 8192*32 ints
    float* out_pre = ws + (size_t)M * QKVW_ + (size_t)M * KNN_; // 8192*256 floats

    float* out_main  = (float*)d_out;               // 8192*256
    float* out_coors = out_main + (size_t)M * DIM_; // 8192*3

    gemm_kernel<<<dim3(QKVW_/64, M/64), 256, 0, stream>>>(feats, w_qkv, nullptr, qkv,
                                                          M, DIM_, QKVW_);
    knn_kernel<<<M, 256, 0, stream>>>(coors, nbhd);
    attn_kernel<<<M, 256, 0, stream>>>(qkv, coors, nbhd, w_c1, b_c1, w_c2, b_c2, ln_b,
                                       out_pre, out_coors);
    gemm_kernel<<<dim3(DIM_/64, M/64), 256, 0, stream>>>(out_pre, w_out, b_out, out_main,
                                                         M, DIM_, DIM_);
}

// Round 8
// 139.023 us; speedup vs baseline: 3.9860x; 1.3090x over previous
//
#include <hip/hip_runtime.h>
#include <hip/hip_fp16.h>
#include <math.h>

#define B_ 2
#define N_ 4096
#define DIM_ 256
#define HEADS_ 4
#define DH_ 64
#define KNN_ 32
#define INNER_ 256       // HEADS*DH
#define QKVW_ 768        // 3*INNER
#define HB_ 512          // histogram bins
#define CAND_ 512        // boundary-bin candidate cap

typedef _Float16 f16x8 __attribute__((ext_vector_type(8)));
typedef _Float16 f16x4 __attribute__((ext_vector_type(4)));
typedef float    f32x4 __attribute__((ext_vector_type(4)));

static __device__ __forceinline__ unsigned long long ullmin2(unsigned long long a, unsigned long long b) {
    return a < b ? a : b;
}

// sin/cos of (2*pi*rev) via HW trans ops; rev >= 0.
static __device__ __forceinline__ void sincos_rev(float rev, float* s, float* c) {
    const float fr = rev - floorf(rev);      // v_fract
    float ss, cc;
    asm("v_sin_f32 %0, %1" : "=v"(ss) : "v"(fr));
    asm("v_cos_f32 %0, %1" : "=v"(cc) : "v"(fr));
    *s = ss; *c = cc;
}

// ---------------- Kernel A: exact KNN via histogram select ----------------
__global__ __launch_bounds__(256) void knn_kernel(const float* __restrict__ coors,
                                                  int* __restrict__ nbhd) {
    __shared__ float dists[N_];                 // 16 KB
    __shared__ int   hist[HB_];                 // 2 KB
    __shared__ unsigned long long cand[CAND_];  // 4 KB
    __shared__ float tminf[256];
    __shared__ float Msh;
    __shared__ int   bsh, clsh, candcnt, outcnt;

    const int bi = blockIdx.x;
    const int b = bi >> 12;            // N_ = 4096
    const int i = bi & (N_ - 1);
    const int t = threadIdx.x;
    const float* cb = coors + (size_t)b * N_ * 3;
    const float xi = cb[i*3+0], yi = cb[i*3+1], zi = cb[i*3+2];

    float mymin = INFINITY;
    #pragma unroll
    for (int l = 0; l < N_/256; ++l) {
        const int j = t + l*256;
        const float dx = xi - cb[j*3+0];
        const float dy = yi - cb[j*3+1];
        const float dz = zi - cb[j*3+2];
        const float d = sqrtf(dx*dx + dy*dy + dz*dz);
        dists[j] = d;
        mymin = fminf(mymin, d);
    }
    tminf[t] = mymin;
    hist[t] = 0; hist[t + 256] = 0;
    if (t == 0) { candcnt = 0; outcnt = 0; }
    __syncthreads();

    if (t < 64) {
        float m4 = fmaxf(fmaxf(tminf[t], tminf[t+64]), fmaxf(tminf[t+128], tminf[t+192]));
        #pragma unroll
        for (int off = 32; off; off >>= 1) m4 = fmaxf(m4, __shfl_xor(m4, off));
        if (t == 0) Msh = fmaxf(m4, 1e-20f);
    }
    __syncthreads();

    const float Mv = Msh;
    const float scale = (float)(HB_ - 1) / Mv;

    // histogram of RELEVANT distances only (d <= M; >=256 dists are <= M so
    // the 32nd smallest is <= M — skipping d > M cannot change selection)
    #pragma unroll
    for (int l = 0; l < N_/256; ++l) {
        const int j = t + l*256;
        const float d = dists[j];
        if (d <= Mv) {
            const int bin = (int)fminf(d * scale, (float)(HB_ - 1));
            atomicAdd(&hist[bin], 1);
        }
    }
    __syncthreads();

    if (t < 64) {
        int s = 0;
        #pragma unroll
        for (int k = 0; k < HB_/64; ++k) s += hist[t*(HB_/64) + k];
        int inc = s;
        #pragma unroll
        for (int off = 1; off < 64; off <<= 1) {
            const int v = __shfl_up(inc, off);
            if (t >= off) inc += v;
        }
        const int excl = inc - s;
        if (excl < KNN_ && inc >= KNN_) {
            int cum = excl;
            #pragma unroll
            for (int k = 0; k < HB_/64; ++k) {
                const int c = hist[t*(HB_/64) + k];
                if (cum + c >= KNN_) { bsh = t*(HB_/64) + k; clsh = cum; break; }
                cum += c;
            }
        }
    }
    __syncthreads();

    const int bbin = bsh, c_less = clsh;

    #pragma unroll
    for (int l = 0; l < N_/256; ++l) {
        const int j = t + l*256;
        const float d = dists[j];
        if (d <= Mv) {
            const int bin = (int)fminf(d * scale, (float)(HB_ - 1));
            if (bin < bbin) {
                const int slot = atomicAdd(&outcnt, 1);
                nbhd[(size_t)bi * KNN_ + slot] = j;
            } else if (bin == bbin) {
                const int c = atomicAdd(&candcnt, 1);
                if (c < CAND_) {
                    cand[c] = ((unsigned long long)__float_as_uint(d) << 32) | (unsigned)j;
                }
            }
        }
    }
    __syncthreads();

    const int m = KNN_ - c_less;
    const int e = candcnt;
    if (e <= CAND_) {
        if (t < 64) {
            for (int r = 0; r < m; ++r) {
                unsigned long long v = ~0ULL;
                for (int idx = t; idx < e; idx += 64) v = ullmin2(v, cand[idx]);
                #pragma unroll
                for (int off = 32; off; off >>= 1) v = ullmin2(v, __shfl_xor(v, off));
                if (t == 0) nbhd[(size_t)bi * KNN_ + c_less + r] = (int)(v & 0xffffffffu);
                for (int idx = t; idx < e; idx += 64)
                    if (cand[idx] == v) cand[idx] = ~0ULL;
            }
        }
    } else if (t == 0) {
        for (int r = 0; r < m; ++r) {
            unsigned long long best = ~0ULL;
            for (int j = 0; j < N_; ++j) {
                const float d = dists[j];
                if (d <= Mv) {
                    const int bin = (int)fminf(d * scale, (float)(HB_ - 1));
                    if (bin == bbin) {
                        const unsigned long long key =
                            ((unsigned long long)__float_as_uint(d) << 32) | (unsigned)j;
                        best = ullmin2(best, key);
                    }
                }
            }
            const int wj = (int)(best & 0xffffffffu);
            nbhd[(size_t)bi * KNN_ + c_less + r] = wj;
            dists[wj] = INFINITY;
        }
    }
}

// ---------------- weight transpose+convert: w[K=256][Nn] f32 -> wT[Nn][256] f16 * 64 ----------------
__global__ __launch_bounds__(256) void wconv_kernel(const float* __restrict__ in,
                                                    _Float16* __restrict__ out,
                                                    int Nn) {
    __shared__ float tl[32][33];
    const int tx = threadIdx.x & 31, ty = threadIdx.x >> 5;
    const int n0 = blockIdx.x * 32, k0 = blockIdx.y * 32;
    #pragma unroll
    for (int r = 0; r < 4; ++r)
        tl[ty + r*8][tx] = in[(size_t)(k0 + ty + r*8) * Nn + n0 + tx];
    __syncthreads();
    #pragma unroll
    for (int r = 0; r < 4; ++r)
        out[(size_t)(n0 + ty + r*8) * 256 + k0 + tx] = (_Float16)(tl[tx][ty + r*8] * 64.0f);
}

// ---------------- MFMA GEMM: C(M x Nn) = A(M x 256, f32) @ BtT /64 + bias ----------------
// Bt: [Nn][256] f16 (weights pre-transposed, pre-scaled x64). A converted to
// f16 in-kernel during LDS staging. 128x128 tile, BK=32, 4 waves, 4x4 frags of
// mfma_f32_16x16x32_f16. C/D layout: col=lane&15, row=(lane>>4)*4+reg.
__global__ __launch_bounds__(256) void mfma_gemm_kernel(const float* __restrict__ A,
                                                        const _Float16* __restrict__ Bt,
                                                        const float* __restrict__ bias,
                                                        float* __restrict__ C,
                                                        int Nn) {
    __shared__ _Float16 As[4096];   // [kgrp][row][8]  (8 KB)
    __shared__ _Float16 Bs[4096];   // [kgrp][col][8]  (8 KB)
    const int t = threadIdx.x;
    const int w = t >> 6, l = t & 63;
    const int wr = w >> 1, wc = w & 1;
    const int lr = l & 15, kg = l >> 4;
    const int row0 = blockIdx.y * 128, col0 = blockIdx.x * 128;

    f32x4 acc[4][4];
    #pragma unroll
    for (int mi = 0; mi < 4; ++mi)
        #pragma unroll
        for (int ni = 0; ni < 4; ++ni)
            acc[mi][ni] = (f32x4){0.0f, 0.0f, 0.0f, 0.0f};

    for (int k0 = 0; k0 < 256; k0 += 32) {
        __syncthreads();
        // stage A with on-the-fly f32->f16: slot=(r*256+t): row=slot>>3, kq=slot&7
        #pragma unroll
        for (int r = 0; r < 4; ++r) {
            const int slot = r*256 + t;
            const int row = slot >> 3, kq = slot & 7;
            const float4 a4 = *(const float4*)(A + (size_t)(row0 + row)*256 + k0 + kq*4);
            f16x4 h;
            h[0] = (_Float16)a4.x; h[1] = (_Float16)a4.y;
            h[2] = (_Float16)a4.z; h[3] = (_Float16)a4.w;
            *(f16x4*)&As[((size_t)((kq>>1)<<7) + row)*8 + (kq&1)*4] = h;
        }
        // stage B (already f16): u=(r*256+t): col=u>>2, kq=u&3
        #pragma unroll
        for (int r = 0; r < 2; ++r) {
            const int u = r*256 + t;
            const int col = u >> 2, kq = u & 3;
            *(f16x8*)&Bs[((size_t)(kq<<7) + col)*8] =
                *(const f16x8*)(Bt + (size_t)(col0 + col)*256 + k0 + kq*8);
        }
        __syncthreads();
        f16x8 af[4], bf[4];
        #pragma unroll
        for (int mi = 0; mi < 4; ++mi)
            af[mi] = *(const f16x8*)&As[((kg<<7) + wr*64 + mi*16 + lr)*8];
        #pragma unroll
        for (int ni = 0; ni < 4; ++ni)
            bf[ni] = *(const f16x8*)&Bs[((kg<<7) + wc*64 + ni*16 + lr)*8];
        #pragma unroll
        for (int mi = 0; mi < 4; ++mi)
            #pragma unroll
            for (int ni = 0; ni < 4; ++ni)
                acc[mi][ni] = __builtin_amdgcn_mfma_f32_16x16x32_f16(af[mi], bf[ni], acc[mi][ni], 0, 0, 0);
    }

    #pragma unroll
    for (int mi = 0; mi < 4; ++mi)
        #pragma unroll
        for (int ni = 0; ni < 4; ++ni) {
            const int col = col0 + wc*64 + ni*16 + lr;
            const float bv = bias ? bias[col] : 0.0f;
            #pragma unroll
            for (int r = 0; r < 4; ++r) {
                const int row = row0 + wr*64 + mi*16 + kg*4 + r;
                C[(size_t)row * Nn + col] = acc[mi][ni][r] * 0.015625f + bv;
            }
        }
}

// ---------------- Kernel C: fused neighbor attention per (b,i) ----------------
__global__ __launch_bounds__(256) void attn_kernel(const float* __restrict__ qkv,
                                                   const float* __restrict__ coors,
                                                   const int* __restrict__ nbhd,
                                                   const float* __restrict__ w_c1,
                                                   const float* __restrict__ b_c1,
                                                   const float* __restrict__ w_c2,
                                                   const float* __restrict__ b_c2,
                                                   const float* __restrict__ ln_b,
                                                   float* __restrict__ out_pre,
                                                   float* __restrict__ coors_out) {
    __shared__ __half vgh[KNN_ * INNER_];   // 16 KB rotated v (f16)
    __shared__ float qkl[KNN_][HEADS_];
    __shared__ float attnl[KNN_][HEADS_];
    __shared__ float coorw[KNN_];
    __shared__ float distl[KNN_];           // holds dist*100
    __shared__ float ul[KNN_][3];
    __shared__ int   njl[KNN_];

    const int bi = blockIdx.x;
    const int b = bi >> 12;
    const int i = bi & (N_ - 1);
    const int t = threadIdx.x;
    const int w = t >> 6;                   // wave id
    const int l = t & 63;                   // lane
    const float* cb = coors + (size_t)b * N_ * 3;

    if (t < KNN_) {
        const int nj = nbhd[(size_t)bi * KNN_ + t];
        njl[t] = nj;
        const float dx = cb[i*3+0] - cb[nj*3+0];
        const float dy = cb[i*3+1] - cb[nj*3+1];
        const float dz = cb[i*3+2] - cb[nj*3+2];
        const float dist = sqrtf(dx*dx + dy*dy + dz*dz);
        distl[t] = dist * 100.0f;
        const float den = fmaxf(dist, 1e-8f);
        ul[t][0] = dx / den; ul[t][1] = dy / den; ul[t][2] = dz / den;
    }

    const float4 q4 = *(const float4*)(qkv + (size_t)bi * QKVW_ + 4*l);
    const int li = l & 15;
    const bool rot = li < 8;
    const float invf0r = exp2f(-(float)(2*li    ) * 0.8304820237218407f) * 0.15915494309189535f;
    const float invf1r = exp2f(-(float)(2*li + 1) * 0.8304820237218407f) * 0.15915494309189535f;
    __syncthreads();

    #pragma unroll 4
    for (int jj = 0; jj < 8; ++jj) {
        const int j = w*8 + jj;
        const int nj = njl[j];
        const float* base = qkv + (size_t)(b * N_ + nj) * QKVW_;
        float4 k4 = *(const float4*)(base + INNER_   + 4*l);
        float4 v4 = *(const float4*)(base + 2*INNER_ + 4*l);
        if (rot) {
            const float d100 = distl[j];
            float s0, c0, s1, c1;
            sincos_rev(d100 * invf0r, &s0, &c0);
            sincos_rev(d100 * invf1r, &s1, &c1);
            float x;
            x = k4.x; k4.x = x*c0 - k4.y*s0; k4.y = k4.y*c0 + x*s0;
            x = k4.z; k4.z = x*c1 - k4.w*s1; k4.w = k4.w*c1 + x*s1;
            x = v4.x; v4.x = x*c0 - v4.y*s0; v4.y = v4.y*c0 + x*s0;
            x = v4.z; v4.z = x*c1 - v4.w*s1; v4.w = v4.w*c1 + x*s1;
        }
        {   // pack v4 -> 4 halfs, single 8 B LDS write
            union { __half2 h2[2]; uint2 u; } pk;
            pk.h2[0] = __floats2half2_rn(v4.x, v4.y);
            pk.h2[1] = __floats2half2_rn(v4.z, v4.w);
            *reinterpret_cast<uint2*>(&vgh[j * INNER_ + 4*l]) = pk.u;
        }
        float p = q4.x*k4.x + q4.y*k4.y + q4.z*k4.z + q4.w*k4.w;
        p += __shfl_xor(p, 1);
        p += __shfl_xor(p, 2);
        p += __shfl_xor(p, 4);
        p += __shfl_xor(p, 8);
        if (li == 0) qkl[j][l >> 4] = p * 0.125f;   // * dh^-0.5
    }
    __syncthreads();

    {
        const int d = l;
        const float x = (d < KNN_) ? qkl[d][w] : -INFINITY;
        float mx = x;
        #pragma unroll
        for (int off = 32; off; off >>= 1) mx = fmaxf(mx, __shfl_xor(mx, off));
        const float e = expf(x - mx);
        float s = e;
        #pragma unroll
        for (int off = 32; off; off >>= 1) s += __shfl_xor(s, off);
        if (d < KNN_) attnl[d][w] = e / s;
    }

    if (t < KNN_) {
        const float q0 = qkl[t][0], q1 = qkl[t][1], q2 = qkl[t][2], q3 = qkl[t][3];
        float cw = b_c2[0];
        #pragma unroll
        for (int mh = 0; mh < 16; ++mh) {
            const float hv = q0*w_c1[0*16+mh] + q1*w_c1[1*16+mh]
                           + q2*w_c1[2*16+mh] + q3*w_c1[3*16+mh] + b_c1[mh];
            const float g = 0.5f * hv * (1.0f + erff(hv * 0.70710678118654752440f));
            cw += g * w_c2[mh];
        }
        coorw[t] = cw;
    }
    __syncthreads();

    float o = 0.0f;
    #pragma unroll
    for (int j = 0; j < KNN_; ++j)
        o += attnl[j][w] * __half2float(vgh[j * INNER_ + t]);
    out_pre[(size_t)bi * INNER_ + t] = o;

    if (t < 3) {
        float acc = 0.0f;
        #pragma unroll
        for (int j = 0; j < KNN_; ++j) acc += coorw[j] * ul[j][t];
        coors_out[(size_t)bi * 3 + t] = acc * ln_b[0];
    }
}

extern "C" void kernel_launch(void* const* d_in, const int* in_sizes, int n_in,
                              void* d_out, int out_size, void* d_ws, size_t ws_size,
                              hipStream_t stream) {
    (void)in_sizes; (void)n_in; (void)out_size; (void)ws_size;
    const float* feats = (const float*)d_in[0];
    const float* coors = (const float*)d_in[1];
    const float* w_qkv = (const float*)d_in[2];
    const float* w_out = (const float*)d_in[3];
    const float* b_out = (const float*)d_in[4];
    const float* w_c1  = (const float*)d_in[5];
    const float* b_c1  = (const float*)d_in[6];
    const float* w_c2  = (const float*)d_in[7];
    const float* b_c2  = (const float*)d_in[8];
    const float* ln_b  = (const float*)d_in[10];   // ln_g (d_in[9]) is dead

    const int M = B_ * N_;                          // 8192
    float* ws      = (float*)d_ws;
    float* qkv     = ws;                                        // 8192*768 f32
    int*   nbhd    = (int*)(ws + (size_t)M * QKVW_);            // 8192*32 int
    float* out_pre = ws + (size_t)M * QKVW_ + (size_t)M * KNN_; // 8192*256 f32
    _Float16* wqkvT = (_Float16*)(out_pre + (size_t)M * INNER_);// 768*256 f16
    _Float16* woutT = wqkvT + (size_t)QKVW_ * DIM_;             // 256*256 f16

    float* out_main  = (float*)d_out;               // 8192*256
    float* out_coors = out_main + (size_t)M * DIM_; // 8192*3

    // weight transpose+convert (f16, x64)
    wconv_kernel<<<dim3(QKVW_/32, DIM_/32), 256, 0, stream>>>(w_qkv, wqkvT, QKVW_);
    wconv_kernel<<<dim3(DIM_/32,  DIM_/32), 256, 0, stream>>>(w_out, woutT, DIM_);

    // qkv = feats @ w_qkv   (MFMA f16)
    mfma_gemm_kernel<<<dim3(QKVW_/128, M/128), 256, 0, stream>>>(feats, wqkvT, nullptr,
                                                                 qkv, QKVW_);
    // exact top-32 neighbors
    knn_kernel<<<M, 256, 0, stream>>>(coors, nbhd);
    // fused neighbor attention + coordinate path
    attn_kernel<<<M, 256, 0, stream>>>(qkv, coors, nbhd, w_c1, b_c1, w_c2, b_c2, ln_b,
                                       out_pre, out_coors);
    // out = out_pre @ w_out + b_out   (MFMA f16)
    mfma_gemm_kernel<<<dim3(DIM_/128, M/128), 256, 0, stream>>>(out_pre, woutT, b_out,
                                                                out_main, DIM_);
}

// Round 9
// 129.638 us; speedup vs baseline: 4.2746x; 1.0724x over previous
//
#include <hip/hip_runtime.h>
#include <hip/hip_fp16.h>
#include <math.h>

#define B_ 2
#define N_ 4096
#define DIM_ 256
#define HEADS_ 4
#define DH_ 64
#define KNN_ 32
#define INNER_ 256       // HEADS*DH
#define QKVW_ 768        // 3*INNER
#define HB_ 512          // histogram bins
#define CAND_ 512        // boundary-bin candidate cap

typedef _Float16 f16x8 __attribute__((ext_vector_type(8)));
typedef _Float16 f16x4 __attribute__((ext_vector_type(4)));
typedef float    f32x4 __attribute__((ext_vector_type(4)));

static __device__ __forceinline__ unsigned long long ullmin2(unsigned long long a, unsigned long long b) {
    return a < b ? a : b;
}

// sin/cos of (2*pi*rev) via HW trans ops; rev >= 0.
static __device__ __forceinline__ void sincos_rev(float rev, float* s, float* c) {
    const float fr = rev - floorf(rev);      // v_fract
    float ss, cc;
    asm("v_sin_f32 %0, %1" : "=v"(ss) : "v"(fr));
    asm("v_cos_f32 %0, %1" : "=v"(cc) : "v"(fr));
    *s = ss; *c = cc;
}

// ---------------- coors AoS -> SoA (x[8192], y[8192], z[8192]) ----------------
__global__ __launch_bounds__(256) void soa_kernel(const float* __restrict__ coors,
                                                  float* __restrict__ xs,
                                                  float* __restrict__ ys,
                                                  float* __restrict__ zs) {
    const int p = blockIdx.x * 256 + threadIdx.x;   // 8192 points
    const float x = coors[p*3+0], y = coors[p*3+1], z = coors[p*3+2];
    xs[p] = x; ys[p] = y; zs[p] = z;
}

// ---------------- Kernel A: exact KNN via histogram select (SoA coords) ----------------
__global__ __launch_bounds__(256) void knn_kernel(const float* __restrict__ xs,
                                                  const float* __restrict__ ys,
                                                  const float* __restrict__ zs,
                                                  int* __restrict__ nbhd) {
    __shared__ float dists[N_];                 // 16 KB
    __shared__ int   hist[HB_];                 // 2 KB
    __shared__ unsigned long long cand[CAND_];  // 4 KB
    __shared__ float tminf[256];
    __shared__ float Msh;
    __shared__ int   bsh, clsh, candcnt, outcnt;

    const int bi = blockIdx.x;
    const int b = bi >> 12;            // N_ = 4096
    const int t = threadIdx.x;
    const float* xb = xs + (size_t)b * N_;
    const float* yb = ys + (size_t)b * N_;
    const float* zb = zs + (size_t)b * N_;
    const float xi = xs[bi], yi = ys[bi], zi = zs[bi];

    // phase 1: all distances (float4 point loads) + per-thread min
    float mymin = INFINITY;
    #pragma unroll
    for (int r = 0; r < N_/(256*4); ++r) {
        const int p = t + r*256;                 // float4 group
        const float4 xv = *(const float4*)(xb + 4*p);
        const float4 yv = *(const float4*)(yb + 4*p);
        const float4 zv = *(const float4*)(zb + 4*p);
        float4 dv;
        {   float dx = xi - xv.x, dy = yi - yv.x, dz = zi - zv.x;
            dv.x = sqrtf(dx*dx + dy*dy + dz*dz); }
        {   float dx = xi - xv.y, dy = yi - yv.y, dz = zi - zv.y;
            dv.y = sqrtf(dx*dx + dy*dy + dz*dz); }
        {   float dx = xi - xv.z, dy = yi - yv.z, dz = zi - zv.z;
            dv.z = sqrtf(dx*dx + dy*dy + dz*dz); }
        {   float dx = xi - xv.w, dy = yi - yv.w, dz = zi - zv.w;
            dv.w = sqrtf(dx*dx + dy*dy + dz*dz); }
        *(float4*)&dists[4*p] = dv;
        mymin = fminf(mymin, fminf(fminf(dv.x, dv.y), fminf(dv.z, dv.w)));
    }
    tminf[t] = mymin;
    hist[t] = 0; hist[t + 256] = 0;
    if (t == 0) { candcnt = 0; outcnt = 0; }
    __syncthreads();

    if (t < 64) {
        float m4 = fmaxf(fmaxf(tminf[t], tminf[t+64]), fmaxf(tminf[t+128], tminf[t+192]));
        #pragma unroll
        for (int off = 32; off; off >>= 1) m4 = fmaxf(m4, __shfl_xor(m4, off));
        if (t == 0) Msh = fmaxf(m4, 1e-20f);
    }
    __syncthreads();

    const float Mv = Msh;
    const float scale = (float)(HB_ - 1) / Mv;

    // histogram of RELEVANT distances only (d <= M; >=256 dists are <= M so
    // the 32nd smallest is <= M — skipping d > M cannot change selection)
    #pragma unroll
    for (int l = 0; l < N_/256; ++l) {
        const int j = t + l*256;
        const float d = dists[j];
        if (d <= Mv) {
            const int bin = (int)fminf(d * scale, (float)(HB_ - 1));
            atomicAdd(&hist[bin], 1);
        }
    }
    __syncthreads();

    if (t < 64) {
        int s = 0;
        #pragma unroll
        for (int k = 0; k < HB_/64; ++k) s += hist[t*(HB_/64) + k];
        int inc = s;
        #pragma unroll
        for (int off = 1; off < 64; off <<= 1) {
            const int v = __shfl_up(inc, off);
            if (t >= off) inc += v;
        }
        const int excl = inc - s;
        if (excl < KNN_ && inc >= KNN_) {
            int cum = excl;
            #pragma unroll
            for (int k = 0; k < HB_/64; ++k) {
                const int c = hist[t*(HB_/64) + k];
                if (cum + c >= KNN_) { bsh = t*(HB_/64) + k; clsh = cum; break; }
                cum += c;
            }
        }
    }
    __syncthreads();

    const int bbin = bsh, c_less = clsh;

    #pragma unroll
    for (int l = 0; l < N_/256; ++l) {
        const int j = t + l*256;
        const float d = dists[j];
        if (d <= Mv) {
            const int bin = (int)fminf(d * scale, (float)(HB_ - 1));
            if (bin < bbin) {
                const int slot = atomicAdd(&outcnt, 1);
                nbhd[(size_t)bi * KNN_ + slot] = j;
            } else if (bin == bbin) {
                const int c = atomicAdd(&candcnt, 1);
                if (c < CAND_) {
                    cand[c] = ((unsigned long long)__float_as_uint(d) << 32) | (unsigned)j;
                }
            }
        }
    }
    __syncthreads();

    const int m = KNN_ - c_less;
    const int e = candcnt;
    if (e <= CAND_) {
        if (t < 64) {
            for (int r = 0; r < m; ++r) {
                unsigned long long v = ~0ULL;
                for (int idx = t; idx < e; idx += 64) v = ullmin2(v, cand[idx]);
                #pragma unroll
                for (int off = 32; off; off >>= 1) v = ullmin2(v, __shfl_xor(v, off));
                if (t == 0) nbhd[(size_t)bi * KNN_ + c_less + r] = (int)(v & 0xffffffffu);
                for (int idx = t; idx < e; idx += 64)
                    if (cand[idx] == v) cand[idx] = ~0ULL;
            }
        }
    } else if (t == 0) {
        for (int r = 0; r < m; ++r) {
            unsigned long long best = ~0ULL;
            for (int j = 0; j < N_; ++j) {
                const float d = dists[j];
                if (d <= Mv) {
                    const int bin = (int)fminf(d * scale, (float)(HB_ - 1));
                    if (bin == bbin) {
                        const unsigned long long key =
                            ((unsigned long long)__float_as_uint(d) << 32) | (unsigned)j;
                        best = ullmin2(best, key);
                    }
                }
            }
            const int wj = (int)(best & 0xffffffffu);
            nbhd[(size_t)bi * KNN_ + c_less + r] = wj;
            dists[wj] = INFINITY;
        }
    }
}

// ---------------- weight transpose+convert: w[K=256][Nn] f32 -> wT[Nn][256] f16 * 64 ----------------
__global__ __launch_bounds__(256) void wconv_kernel(const float* __restrict__ in,
                                                    _Float16* __restrict__ out,
                                                    int Nn) {
    __shared__ float tl[32][33];
    const int tx = threadIdx.x & 31, ty = threadIdx.x >> 5;
    const int n0 = blockIdx.x * 32, k0 = blockIdx.y * 32;
    #pragma unroll
    for (int r = 0; r < 4; ++r)
        tl[ty + r*8][tx] = in[(size_t)(k0 + ty + r*8) * Nn + n0 + tx];
    __syncthreads();
    #pragma unroll
    for (int r = 0; r < 4; ++r)
        out[(size_t)(n0 + ty + r*8) * 256 + k0 + tx] = (_Float16)(tl[tx][ty + r*8] * 64.0f);
}

// ---------------- MFMA GEMM: C(M x Nn) = A(M x 256) @ BtT /64 + bias ----------------
// Bt: [Nn][256] f16 (pre-transposed, pre-scaled x64). A f32 (convert in
// staging) or f16 (direct copy). Output f32 or f16 (x 1/64).
// 128x128 tile, BK=32, 4 waves, 4x4 frags of mfma_f32_16x16x32_f16.
// C/D layout: col=lane&15, row=(lane>>4)*4+reg.
template <bool A_F16, bool OUT_F16>
__global__ __launch_bounds__(256) void mfma_gemm_kernel(const void* __restrict__ Ap,
                                                        const _Float16* __restrict__ Bt,
                                                        const float* __restrict__ bias,
                                                        void* __restrict__ Cp,
                                                        int Nn) {
    __shared__ _Float16 As[4096];   // [kgrp][row][8]  (8 KB)
    __shared__ _Float16 Bs[4096];   // [kgrp][col][8]  (8 KB)
    const int t = threadIdx.x;
    const int w = t >> 6, l = t & 63;
    const int wr = w >> 1, wc = w & 1;
    const int lr = l & 15, kg = l >> 4;
    const int row0 = blockIdx.y * 128, col0 = blockIdx.x * 128;

    f32x4 acc[4][4];
    #pragma unroll
    for (int mi = 0; mi < 4; ++mi)
        #pragma unroll
        for (int ni = 0; ni < 4; ++ni)
            acc[mi][ni] = (f32x4){0.0f, 0.0f, 0.0f, 0.0f};

    for (int k0 = 0; k0 < 256; k0 += 32) {
        __syncthreads();
        if constexpr (A_F16) {
            const _Float16* A = (const _Float16*)Ap;
            #pragma unroll
            for (int r = 0; r < 2; ++r) {
                const int u = r*256 + t;
                const int row = u >> 2, kgrp = u & 3;
                *(f16x8*)&As[((kgrp<<7) + row)*8] =
                    *(const f16x8*)(A + (size_t)(row0 + row)*256 + k0 + kgrp*8);
            }
        } else {
            const float* A = (const float*)Ap;
            #pragma unroll
            for (int r = 0; r < 4; ++r) {
                const int slot = r*256 + t;
                const int row = slot >> 3, kq = slot & 7;
                const float4 a4 = *(const float4*)(A + (size_t)(row0 + row)*256 + k0 + kq*4);
                f16x4 h;
                h[0] = (_Float16)a4.x; h[1] = (_Float16)a4.y;
                h[2] = (_Float16)a4.z; h[3] = (_Float16)a4.w;
                *(f16x4*)&As[((size_t)((kq>>1)<<7) + row)*8 + (kq&1)*4] = h;
            }
        }
        #pragma unroll
        for (int r = 0; r < 2; ++r) {
            const int u = r*256 + t;
            const int col = u >> 2, kq = u & 3;
            *(f16x8*)&Bs[((size_t)(kq<<7) + col)*8] =
                *(const f16x8*)(Bt + (size_t)(col0 + col)*256 + k0 + kq*8);
        }
        __syncthreads();
        f16x8 af[4], bf[4];
        #pragma unroll
        for (int mi = 0; mi < 4; ++mi)
            af[mi] = *(const f16x8*)&As[((kg<<7) + wr*64 + mi*16 + lr)*8];
        #pragma unroll
        for (int ni = 0; ni < 4; ++ni)
            bf[ni] = *(const f16x8*)&Bs[((kg<<7) + wc*64 + ni*16 + lr)*8];
        #pragma unroll
        for (int mi = 0; mi < 4; ++mi)
            #pragma unroll
            for (int ni = 0; ni < 4; ++ni)
                acc[mi][ni] = __builtin_amdgcn_mfma_f32_16x16x32_f16(af[mi], bf[ni], acc[mi][ni], 0, 0, 0);
    }

    #pragma unroll
    for (int mi = 0; mi < 4; ++mi)
        #pragma unroll
        for (int ni = 0; ni < 4; ++ni) {
            const int col = col0 + wc*64 + ni*16 + lr;
            const float bv = bias ? bias[col] : 0.0f;
            #pragma unroll
            for (int r = 0; r < 4; ++r) {
                const int row = row0 + wr*64 + mi*16 + kg*4 + r;
                const float v = acc[mi][ni][r] * 0.015625f + bv;
                if constexpr (OUT_F16)
                    ((_Float16*)Cp)[(size_t)row * Nn + col] = (_Float16)v;
                else
                    ((float*)Cp)[(size_t)row * Nn + col] = v;
            }
        }
}

// ---------------- Kernel C: fused neighbor attention per (b,i), f16 qkv ----------------
__global__ __launch_bounds__(256) void attn_kernel(const _Float16* __restrict__ qkv,
                                                   const float* __restrict__ coors,
                                                   const int* __restrict__ nbhd,
                                                   const float* __restrict__ w_c1,
                                                   const float* __restrict__ b_c1,
                                                   const float* __restrict__ w_c2,
                                                   const float* __restrict__ b_c2,
                                                   const float* __restrict__ ln_b,
                                                   _Float16* __restrict__ out_pre,
                                                   float* __restrict__ coors_out) {
    __shared__ __half vgh[KNN_ * INNER_];   // 16 KB rotated v (f16)
    __shared__ float qkl[KNN_][HEADS_];
    __shared__ float attnl[KNN_][HEADS_];
    __shared__ float coorw[KNN_];
    __shared__ float distl[KNN_];           // holds dist*100
    __shared__ float ul[KNN_][3];
    __shared__ int   njl[KNN_];

    const int bi = blockIdx.x;
    const int b = bi >> 12;
    const int i = bi & (N_ - 1);
    const int t = threadIdx.x;
    const int w = t >> 6;                   // wave id
    const int l = t & 63;                   // lane
    const float* cb = coors + (size_t)b * N_ * 3;

    if (t < KNN_) {
        const int nj = nbhd[(size_t)bi * KNN_ + t];
        njl[t] = nj;
        const float dx = cb[i*3+0] - cb[nj*3+0];
        const float dy = cb[i*3+1] - cb[nj*3+1];
        const float dz = cb[i*3+2] - cb[nj*3+2];
        const float dist = sqrtf(dx*dx + dy*dy + dz*dz);
        distl[t] = dist * 100.0f;
        const float den = fmaxf(dist, 1e-8f);
        ul[t][0] = dx / den; ul[t][1] = dy / den; ul[t][2] = dz / den;
    }

    const f16x4 qh = *(const f16x4*)(qkv + (size_t)bi * QKVW_ + 4*l);
    const float q0 = (float)qh[0], q1 = (float)qh[1], q2 = (float)qh[2], q3 = (float)qh[3];
    const int li = l & 15;
    const bool rot = li < 8;
    const float invf0r = exp2f(-(float)(2*li    ) * 0.8304820237218407f) * 0.15915494309189535f;
    const float invf1r = exp2f(-(float)(2*li + 1) * 0.8304820237218407f) * 0.15915494309189535f;
    __syncthreads();

    #pragma unroll 4
    for (int jj = 0; jj < 8; ++jj) {
        const int j = w*8 + jj;
        const int nj = njl[j];
        const _Float16* base = qkv + (size_t)(b * N_ + nj) * QKVW_;
        const f16x4 kh = *(const f16x4*)(base + INNER_   + 4*l);
        const f16x4 vh = *(const f16x4*)(base + 2*INNER_ + 4*l);
        float kx = (float)kh[0], ky = (float)kh[1], kz = (float)kh[2], kw = (float)kh[3];
        float vx = (float)vh[0], vy = (float)vh[1], vz = (float)vh[2], vw = (float)vh[3];
        if (rot) {
            const float d100 = distl[j];
            float s0, c0, s1, c1;
            sincos_rev(d100 * invf0r, &s0, &c0);
            sincos_rev(d100 * invf1r, &s1, &c1);
            float x;
            x = kx; kx = x*c0 - ky*s0; ky = ky*c0 + x*s0;
            x = kz; kz = x*c1 - kw*s1; kw = kw*c1 + x*s1;
            x = vx; vx = x*c0 - vy*s0; vy = vy*c0 + x*s0;
            x = vz; vz = x*c1 - vw*s1; vw = vw*c1 + x*s1;
        }
        {   // pack v -> 4 halfs, single 8 B LDS write
            union { __half2 h2[2]; uint2 u; } pk;
            pk.h2[0] = __floats2half2_rn(vx, vy);
            pk.h2[1] = __floats2half2_rn(vz, vw);
            *reinterpret_cast<uint2*>(&vgh[j * INNER_ + 4*l]) = pk.u;
        }
        float p = q0*kx + q1*ky + q2*kz + q3*kw;
        p += __shfl_xor(p, 1);
        p += __shfl_xor(p, 2);
        p += __shfl_xor(p, 4);
        p += __shfl_xor(p, 8);
        if (li == 0) qkl[j][l >> 4] = p * 0.125f;   // * dh^-0.5
    }
    __syncthreads();

    {
        const int d = l;
        const float x = (d < KNN_) ? qkl[d][w] : -INFINITY;
        float mx = x;
        #pragma unroll
        for (int off = 32; off; off >>= 1) mx = fmaxf(mx, __shfl_xor(mx, off));
        const float e = expf(x - mx);
        float s = e;
        #pragma unroll
        for (int off = 32; off; off >>= 1) s += __shfl_xor(s, off);
        if (d < KNN_) attnl[d][w] = e / s;
    }

    if (t < KNN_) {
        const float a0 = qkl[t][0], a1 = qkl[t][1], a2 = qkl[t][2], a3 = qkl[t][3];
        float cw = b_c2[0];
        #pragma unroll
        for (int mh = 0; mh < 16; ++mh) {
            const float hv = a0*w_c1[0*16+mh] + a1*w_c1[1*16+mh]
                           + a2*w_c1[2*16+mh] + a3*w_c1[3*16+mh] + b_c1[mh];
            const float g = 0.5f * hv * (1.0f + erff(hv * 0.70710678118654752440f));
            cw += g * w_c2[mh];
        }
        coorw[t] = cw;
    }
    __syncthreads();

    float o = 0.0f;
    #pragma unroll
    for (int j = 0; j < KNN_; ++j)
        o += attnl[j][w] * __half2float(vgh[j * INNER_ + t]);
    out_pre[(size_t)bi * INNER_ + t] = (_Float16)o;

    if (t < 3) {
        float acc = 0.0f;
        #pragma unroll
        for (int j = 0; j < KNN_; ++j) acc += coorw[j] * ul[j][t];
        coors_out[(size_t)bi * 3 + t] = acc * ln_b[0];
    }
}

extern "C" void kernel_launch(void* const* d_in, const int* in_sizes, int n_in,
                              void* d_out, int out_size, void* d_ws, size_t ws_size,
                              hipStream_t stream) {
    (void)in_sizes; (void)n_in; (void)out_size; (void)ws_size;
    const float* feats = (const float*)d_in[0];
    const float* coors = (const float*)d_in[1];
    const float* w_qkv = (const float*)d_in[2];
    const float* w_out = (const float*)d_in[3];
    const float* b_out = (const float*)d_in[4];
    const float* w_c1  = (const float*)d_in[5];
    const float* b_c1  = (const float*)d_in[6];
    const float* w_c2  = (const float*)d_in[7];
    const float* b_c2  = (const float*)d_in[8];
    const float* ln_b  = (const float*)d_in[10];   // ln_g (d_in[9]) is dead

    const int M = B_ * N_;                          // 8192
    _Float16* qkv_h    = (_Float16*)d_ws;                         // M*768 f16
    int*      nbhd     = (int*)(qkv_h + (size_t)M * QKVW_);       // M*32 int
    _Float16* out_pre  = (_Float16*)(nbhd + (size_t)M * KNN_);    // M*256 f16
    _Float16* wqkvT    = out_pre + (size_t)M * INNER_;            // 768*256 f16
    _Float16* woutT    = wqkvT + (size_t)QKVW_ * DIM_;            // 256*256 f16
    float*    xs       = (float*)(woutT + (size_t)DIM_ * DIM_);   // M
    float*    ys       = xs + M;
    float*    zs       = ys + M;

    float* out_main  = (float*)d_out;               // 8192*256
    float* out_coors = out_main + (size_t)M * DIM_; // 8192*3

    // weight transpose+convert (f16, x64) + coords SoA
    wconv_kernel<<<dim3(QKVW_/32, DIM_/32), 256, 0, stream>>>(w_qkv, wqkvT, QKVW_);
    wconv_kernel<<<dim3(DIM_/32,  DIM_/32), 256, 0, stream>>>(w_out, woutT, DIM_);
    soa_kernel<<<M/256, 256, 0, stream>>>(coors, xs, ys, zs);

    // qkv = feats @ w_qkv   (MFMA f16, f16 output)
    mfma_gemm_kernel<false, true><<<dim3(QKVW_/128, M/128), 256, 0, stream>>>(
        feats, wqkvT, nullptr, qkv_h, QKVW_);
    // exact top-32 neighbors
    knn_kernel<<<M, 256, 0, stream>>>(xs, ys, zs, nbhd);
    // fused neighbor attention + coordinate path
    attn_kernel<<<M, 256, 0, stream>>>(qkv_h, coors, nbhd, w_c1, b_c1, w_c2, b_c2, ln_b,
                                       out_pre, out_coors);
    // out = out_pre @ w_out + b_out   (MFMA f16 A, f32 output)
    mfma_gemm_kernel<true, false><<<dim3(DIM_/128, M/128), 256, 0, stream>>>(
        out_pre, woutT, b_out, out_main, DIM_);
}